// Round 1
// baseline (3201.508 us; speedup 1.0000x reference)
//
#include <hip/hip_runtime.h>
#include <math.h>

#define NQ 2048
#define MKV 2048
#define BZ 2
#define DM 1024
#define NH 16
#define DH 64
#define RTAB 4095  /* NQ + MKV - 1 */

// ---------------- sincos table ----------------
// sc[r*1024 + b] = b<512 ? sin((r-2047)*invfreq[b]) : cos((r-2047)*invfreq[b-512])
__global__ __launch_bounds__(256) void sincos_kernel(float* __restrict__ sc) {
  int idx = blockIdx.x * 256 + threadIdx.x;
  if (idx >= RTAB * DM) return;
  int r = idx / DM;
  int b = idx - r * DM;
  int i = (b < DM / 2) ? b : (b - DM / 2);
  // inv_freq = 10000^(-i/512), computed in double then rounded (matches numpy fp32 to ~1ulp)
  double fr = exp((double)i * (-9.210340371976184 / 512.0));
  float rr = (float)(r - (MKV - 1));
  float ph = rr * (float)fr;
  sc[idx] = (b < DM / 2) ? sinf(ph) : cosf(ph);
}

// ---------------- generic NT GEMM: C[M][N] = sum_k A[M][K] * B[N][K] ----------------
// 64x64 tile, 256 threads, 4x4 per thread, K-tile 16.
__global__ __launch_bounds__(256) void gemm_nt(const float* __restrict__ A,
                                               const float* __restrict__ B,
                                               float* __restrict__ C,
                                               int M, int N, int K) {
  __shared__ float As[64][17];
  __shared__ float Bs[64][17];
  const int t = threadIdx.x;
  const int tx = t & 15;
  const int ty = t >> 4;
  const int row0 = blockIdx.y * 64;
  const int col0 = blockIdx.x * 64;
  const int lr = t >> 2;         // 0..63
  const int lk = (t & 3) << 2;   // 0,4,8,12
  float acc[4][4] = {};
  for (int k0 = 0; k0 < K; k0 += 16) {
    float4 av = make_float4(0.f, 0.f, 0.f, 0.f);
    if (row0 + lr < M)
      av = *(const float4*)(A + (size_t)(row0 + lr) * K + k0 + lk);
    float4 bv = *(const float4*)(B + (size_t)(col0 + lr) * K + k0 + lk);
    As[lr][lk + 0] = av.x; As[lr][lk + 1] = av.y; As[lr][lk + 2] = av.z; As[lr][lk + 3] = av.w;
    Bs[lr][lk + 0] = bv.x; Bs[lr][lk + 1] = bv.y; Bs[lr][lk + 2] = bv.z; Bs[lr][lk + 3] = bv.w;
    __syncthreads();
#pragma unroll
    for (int kk = 0; kk < 16; ++kk) {
      float a[4], b[4];
#pragma unroll
      for (int r = 0; r < 4; ++r) a[r] = As[ty * 4 + r][kk];
#pragma unroll
      for (int c = 0; c < 4; ++c) b[c] = Bs[tx * 4 + c][kk];
#pragma unroll
      for (int r = 0; r < 4; ++r)
#pragma unroll
        for (int c = 0; c < 4; ++c) acc[r][c] += a[r] * b[c];
    }
    __syncthreads();
  }
#pragma unroll
  for (int r = 0; r < 4; ++r) {
    int row = row0 + ty * 4 + r;
    if (row < M) {
      float4 o = make_float4(acc[r][0], acc[r][1], acc[r][2], acc[r][3]);
      *(float4*)(C + (size_t)row * N + col0 + tx * 4) = o;
    }
  }
}

// ---------------- fused causal attention with relative positions ----------------
// q:    [(NQ*BZ)][NH*64]   row nz = n*BZ+z, col h*64+d
// kv:   [(MKV*BZ)][NH*128] row mz = m*BZ+z, col h*128+{d | 64+d}
// tab:  [RTAB][NH*64]
// attn: [(NQ*BZ)][NH*64]
__global__ __launch_bounds__(256) void attn_kernel(const float* __restrict__ q,
                                                   const float* __restrict__ kv,
                                                   const float* __restrict__ tab,
                                                   float* __restrict__ attn) {
  const int qb = (int)gridDim.x - 1 - (int)blockIdx.x;  // heavy blocks first
  const int z = blockIdx.y;
  const int h = blockIdx.z;
  const int n0 = qb * 64;

  __shared__ float qs[64][65];
  __shared__ float ks[64][65];
  __shared__ float vs[64][65];
  __shared__ float ts[127][65];
  __shared__ float ps[64][65];
  __shared__ float mi[64], li[64], al[64];

  const int t = threadIdx.x;
  const int tx = t & 15;
  const int ty = t >> 4;

  // load q tile (64 rows x 64 cols)
#pragma unroll
  for (int it = 0; it < 4; ++it) {
    int f4 = it * 256 + t;
    int i = f4 >> 4;
    int d4 = (f4 & 15) << 2;
    float4 v4 = *(const float4*)(q + (size_t)((n0 + i) * BZ + z) * (NH * 64) + h * 64 + d4);
    qs[i][d4 + 0] = v4.x; qs[i][d4 + 1] = v4.y; qs[i][d4 + 2] = v4.z; qs[i][d4 + 3] = v4.w;
  }
  if (t < 64) { mi[t] = -1e30f; li[t] = 0.f; }

  float acc[4][4] = {};

  for (int mt = 0; mt <= qb; ++mt) {
    const int m0 = mt * 64;
    const int Wb = n0 - m0 + MKV - 64;  // table window base; rows Wb..Wb+126 used
    // load K and V tiles
#pragma unroll
    for (int it = 0; it < 4; ++it) {
      int f4 = it * 256 + t;
      int j = f4 >> 4;
      int d4 = (f4 & 15) << 2;
      const float* base = kv + (size_t)((m0 + j) * BZ + z) * (NH * 128) + h * 128;
      float4 k4 = *(const float4*)(base + d4);
      float4 v4 = *(const float4*)(base + 64 + d4);
      ks[j][d4 + 0] = k4.x; ks[j][d4 + 1] = k4.y; ks[j][d4 + 2] = k4.z; ks[j][d4 + 3] = k4.w;
      vs[j][d4 + 0] = v4.x; vs[j][d4 + 1] = v4.y; vs[j][d4 + 2] = v4.z; vs[j][d4 + 3] = v4.w;
    }
    // load table window: 127 rows x 64 = 2032 float4s
#pragma unroll
    for (int it = 0; it < 8; ++it) {
      int f4 = it * 256 + t;
      if (f4 < 127 * 16) {
        int rr = f4 >> 4;
        int d4 = (f4 & 15) << 2;
        float4 tv = *(const float4*)(tab + (size_t)(Wb + rr) * (NH * 64) + h * 64 + d4);
        ts[rr][d4 + 0] = tv.x; ts[rr][d4 + 1] = tv.y; ts[rr][d4 + 2] = tv.z; ts[rr][d4 + 3] = tv.w;
      }
    }
    __syncthreads();

    // S = q k^T + q t^T   (4x4 per thread)
    float s[4][4] = {};
    for (int d = 0; d < 64; ++d) {
      float qa[4], kb[4];
#pragma unroll
      for (int r = 0; r < 4; ++r) qa[r] = qs[ty * 4 + r][d];
#pragma unroll
      for (int c = 0; c < 4; ++c) kb[c] = ks[tx * 4 + c][d];
#pragma unroll
      for (int r = 0; r < 4; ++r)
#pragma unroll
        for (int c = 0; c < 4; ++c) {
          s[r][c] += qa[r] * kb[c];
          s[r][c] += qa[r] * ts[(ty * 4 + r) - (tx * 4 + c) + 63][d];
        }
    }
    if (mt == qb) {  // diagonal tile: mask j > i
#pragma unroll
      for (int r = 0; r < 4; ++r)
#pragma unroll
        for (int c = 0; c < 4; ++c)
          if ((tx * 4 + c) > (ty * 4 + r)) s[r][c] = -1e30f;
    }
#pragma unroll
    for (int r = 0; r < 4; ++r)
#pragma unroll
      for (int c = 0; c < 4; ++c) ps[ty * 4 + r][tx * 4 + c] = s[r][c];
    __syncthreads();

    // online softmax: one wave per row, 16 rows per wave
    {
      const int wid = t >> 6;
      const int lane = t & 63;
      for (int ii = 0; ii < 16; ++ii) {
        int i = wid * 16 + ii;
        float val = ps[i][lane];
        float mt_ = val;
#pragma unroll
        for (int off = 32; off >= 1; off >>= 1) mt_ = fmaxf(mt_, __shfl_xor(mt_, off));
        float mo = mi[i];
        float mn = fmaxf(mo, mt_);
        float p = __expf(val - mn);
        float lt = p;
#pragma unroll
        for (int off = 32; off >= 1; off >>= 1) lt += __shfl_xor(lt, off);
        ps[i][lane] = p;
        if (lane == 0) {
          float a = __expf(mo - mn);
          al[i] = a;
          li[i] = li[i] * a + lt;
          mi[i] = mn;
        }
      }
    }
    __syncthreads();

    // acc = acc*alpha + P @ V
    {
      float ar[4];
#pragma unroll
      for (int r = 0; r < 4; ++r) ar[r] = al[ty * 4 + r];
#pragma unroll
      for (int r = 0; r < 4; ++r)
#pragma unroll
        for (int c = 0; c < 4; ++c) acc[r][c] *= ar[r];
      for (int j = 0; j < 64; ++j) {
        float pv[4], vb[4];
#pragma unroll
        for (int r = 0; r < 4; ++r) pv[r] = ps[ty * 4 + r][j];
#pragma unroll
        for (int c = 0; c < 4; ++c) vb[c] = vs[j][tx * 4 + c];
#pragma unroll
        for (int r = 0; r < 4; ++r)
#pragma unroll
          for (int c = 0; c < 4; ++c) acc[r][c] += pv[r] * vb[c];
      }
    }
    __syncthreads();
  }

  // write attn = acc / li
#pragma unroll
  for (int r = 0; r < 4; ++r) {
    int i = ty * 4 + r;
    float inv = 1.0f / li[i];
    float4 o = make_float4(acc[r][0] * inv, acc[r][1] * inv, acc[r][2] * inv, acc[r][3] * inv);
    *(float4*)(attn + (size_t)((n0 + i) * BZ + z) * (NH * 64) + h * 64 + tx * 4) = o;
  }
}

// ---------------- launch ----------------
extern "C" void kernel_launch(void* const* d_in, const int* in_sizes, int n_in,
                              void* d_out, int out_size, void* d_ws, size_t ws_size,
                              hipStream_t stream) {
  const float* x_q   = (const float*)d_in[0];
  const float* x_kv  = (const float*)d_in[1];
  const float* to_q  = (const float*)d_in[2];
  const float* to_kv = (const float*)d_in[3];
  const float* fpe   = (const float*)d_in[4];
  const float* to_o  = (const float*)d_in[5];
  float* out = (float*)d_out;

  float* ws = (float*)d_ws;
  float* qbuf   = ws;                          // 4096*1024
  float* kvbuf  = qbuf + (size_t)4096 * 1024;  // 4096*2048
  float* tabbuf = kvbuf + (size_t)4096 * 2048; // 4095*1024 (padded to 4096*1024)
  float* scbuf  = tabbuf + (size_t)4096 * 1024;// sincos first, attn later (aliased)

  // 1. sincos
  sincos_kernel<<<dim3((RTAB * DM + 255) / 256), dim3(256), 0, stream>>>(scbuf);
  // 2. table = sincos @ fpe^T   (4095 x 1024 x 1024)
  gemm_nt<<<dim3(1024 / 64, (RTAB + 63) / 64), dim3(256), 0, stream>>>(
      scbuf, fpe, tabbuf, RTAB, 1024, 1024);
  // 3. q = x_q @ to_q^T         (4096 x 1024 x 1024)
  gemm_nt<<<dim3(1024 / 64, 4096 / 64), dim3(256), 0, stream>>>(
      x_q, to_q, qbuf, 4096, 1024, 1024);
  // 4. kv = x_kv @ to_kv^T      (4096 x 2048 x 1024)
  gemm_nt<<<dim3(2048 / 64, 4096 / 64), dim3(256), 0, stream>>>(
      x_kv, to_kv, kvbuf, 4096, 2048, 1024);
  // 5. attention -> scbuf (sincos no longer needed)
  attn_kernel<<<dim3(NQ / 64, BZ, NH), dim3(256), 0, stream>>>(qbuf, kvbuf, tabbuf, scbuf);
  // 6. out = attn @ to_o^T      (4096 x 1024 x 1024)
  gemm_nt<<<dim3(1024 / 64, 4096 / 64), dim3(256), 0, stream>>>(
      scbuf, to_o, out, 4096, 1024, 1024);
}

// Round 2
// 1756.616 us; speedup vs baseline: 1.8225x; 1.8225x over previous
//
#include <hip/hip_runtime.h>
#include <math.h>

#define NQ 2048
#define MKV 2048
#define BZ 2
#define DM 1024
#define NH 16
#define DH 64
#define RTAB 4095  /* NQ + MKV - 1 */
#define R0TAB 1984 /* lowest table row reachable under causal mask */

// ---------------- sincos table (rows R0TAB..4094 only) ----------------
__global__ __launch_bounds__(256) void sincos_kernel(float* __restrict__ sc) {
  int idx = blockIdx.x * 256 + threadIdx.x;
  if (idx >= (RTAB - R0TAB) * DM) return;
  int r = R0TAB + idx / DM;
  int b = idx - (r - R0TAB) * DM;
  int i = (b < DM / 2) ? b : (b - DM / 2);
  double fr = exp((double)i * (-9.210340371976184 / 512.0));
  float rr = (float)(r - (MKV - 1));
  float ph = rr * (float)fr;
  sc[(size_t)r * DM + b] = (b < DM / 2) ? sinf(ph) : cosf(ph);
}

// ---------------- NT GEMM: C[M][N] = sum_k A[M][K] * B[N][K] ----------------
// 128x128 tile, 256 threads, 8x8 per thread (row = g+16r, col = tx+16c), BK=16.
__global__ __launch_bounds__(256) void gemm_nt(const float* __restrict__ A,
                                               const float* __restrict__ B,
                                               float* __restrict__ C,
                                               int M, int N, int K) {
  __shared__ float As[128][20];
  __shared__ float Bs[128][20];
  const int t = threadIdx.x;
  const int g = t >> 4;
  const int tx = t & 15;
  const int row0 = blockIdx.y * 128;
  const int col0 = blockIdx.x * 128;
  const int lr = t >> 2;        // 0..63
  const int lk = (t & 3) << 2;  // 0,4,8,12
  float acc[8][8] = {};
  for (int k0 = 0; k0 < K; k0 += 16) {
#pragma unroll
    for (int half = 0; half < 2; ++half) {
      int r = half * 64 + lr;
      float4 av = make_float4(0.f, 0.f, 0.f, 0.f);
      if (row0 + r < M) av = *(const float4*)(A + (size_t)(row0 + r) * K + k0 + lk);
      float4 bv = *(const float4*)(B + (size_t)(col0 + r) * K + k0 + lk);
      *(float4*)&As[r][lk] = av;
      *(float4*)&Bs[r][lk] = bv;
    }
    __syncthreads();
#pragma unroll
    for (int kq = 0; kq < 16; kq += 2) {
      float2 a2[8], b2[8];
#pragma unroll
      for (int r = 0; r < 8; ++r) a2[r] = *(const float2*)&As[g + 16 * r][kq];
#pragma unroll
      for (int c = 0; c < 8; ++c) b2[c] = *(const float2*)&Bs[tx + 16 * c][kq];
#pragma unroll
      for (int r = 0; r < 8; ++r)
#pragma unroll
        for (int c = 0; c < 8; ++c) {
          acc[r][c] += a2[r].x * b2[c].x;
          acc[r][c] += a2[r].y * b2[c].y;
        }
    }
    __syncthreads();
  }
#pragma unroll
  for (int r = 0; r < 8; ++r) {
    int row = row0 + g + 16 * r;
    if (row < M) {
#pragma unroll
      for (int c = 0; c < 8; ++c)
        C[(size_t)row * N + col0 + tx + 16 * c] = acc[r][c];
    }
  }
}

// ---------------- fused causal attention with relative positions ----------------
// q:    [(NQ*BZ)][NH*64], kv: [(MKV*BZ)][NH*128], tab: [RTAB][NH*64] (rows>=R0TAB)
// attn: [(NQ*BZ)][NH*64]
__global__ __launch_bounds__(256, 2) void attn_kernel(const float* __restrict__ q,
                                                      const float* __restrict__ kv,
                                                      const float* __restrict__ tab,
                                                      float* __restrict__ attn) {
  const int qb = (int)gridDim.x - 1 - (int)blockIdx.x;  // heavy blocks first
  const int z = blockIdx.y;
  const int h = blockIdx.z;
  const int n0 = qb * 64;

  __shared__ float qs[64][68];
  __shared__ float kvs[64][68];    // K during S-phase; V during PV-phase
  __shared__ float tsps[127][68];  // pos-table during S; P (rows 0..63) during PV

  const int t = threadIdx.x;
  const int g = t >> 4;    // row-group 0..15 (16-lane shuffle group)
  const int tx = t & 15;   // col-group
  const int tbase = g - tx + 63;

  // load Q tile (64x64)
#pragma unroll
  for (int it = 0; it < 4; ++it) {
    int f4 = it * 256 + t;
    int i = f4 >> 4;
    int d4 = (f4 & 15) << 2;
    float4 v4 = *(const float4*)(q + (size_t)((n0 + i) * BZ + z) * DM + h * DH + d4);
    *(float4*)&qs[i][d4] = v4;
  }

  float mi[4], li[4];
#pragma unroll
  for (int r = 0; r < 4; ++r) { mi[r] = -1e30f; li[r] = 0.f; }
  float acc[4][4] = {};

  for (int mt = 0; mt <= qb; ++mt) {
    const int m0 = mt * 64;
    const int Wb = n0 - m0 + R0TAB;  // table window base (127 rows used)
    __syncthreads();  // protect kvs/tsps from previous iteration's PV readers

    // stage K -> kvs, table -> tsps; V -> registers
    float4 vreg[4];
#pragma unroll
    for (int it = 0; it < 4; ++it) {
      int f4 = it * 256 + t;
      int j = f4 >> 4;
      int d4 = (f4 & 15) << 2;
      const float* base = kv + (size_t)((m0 + j) * BZ + z) * (NH * 2 * DH) + h * (2 * DH);
      float4 k4 = *(const float4*)(base + d4);
      vreg[it] = *(const float4*)(base + DH + d4);
      *(float4*)&kvs[j][d4] = k4;
    }
#pragma unroll
    for (int it = 0; it < 8; ++it) {
      int f4 = it * 256 + t;
      if (f4 < 127 * 16) {
        int rr = f4 >> 4;
        int d4 = (f4 & 15) << 2;
        float4 tv = *(const float4*)(tab + (size_t)(Wb + rr) * DM + h * DH + d4);
        *(float4*)&tsps[rr][d4] = tv;
      }
    }
    __syncthreads();

    // S = Q K^T + Q T^T (4x4 per thread, rows g+16r, cols tx+16c)
    float s[4][4] = {};
#pragma unroll 4
    for (int d0 = 0; d0 < 64; d0 += 4) {
      float qa[4][4], kb[4][4], tv[7][4];
#pragma unroll
      for (int r = 0; r < 4; ++r) *(float4*)qa[r] = *(const float4*)&qs[g + 16 * r][d0];
#pragma unroll
      for (int c = 0; c < 4; ++c) *(float4*)kb[c] = *(const float4*)&kvs[tx + 16 * c][d0];
#pragma unroll
      for (int u = 0; u < 7; ++u) *(float4*)tv[u] = *(const float4*)&tsps[tbase + 16 * u - 48][d0];
#pragma unroll
      for (int r = 0; r < 4; ++r)
#pragma unroll
        for (int c = 0; c < 4; ++c) {
#pragma unroll
          for (int e = 0; e < 4; ++e)
            s[r][c] += qa[r][e] * (kb[c][e] + tv[r - c + 3][e]);
        }
    }

    if (mt == qb) {  // diagonal tile: mask j > i
#pragma unroll
      for (int r = 0; r < 4; ++r)
#pragma unroll
        for (int c = 0; c < 4; ++c)
          if (tx + 16 * c > g + 16 * r) s[r][c] = -1e30f;
    }

    // online softmax fully in registers (16-lane group owns each row)
#pragma unroll
    for (int r = 0; r < 4; ++r) {
      float pm = fmaxf(fmaxf(s[r][0], s[r][1]), fmaxf(s[r][2], s[r][3]));
      pm = fmaxf(pm, __shfl_xor(pm, 1));
      pm = fmaxf(pm, __shfl_xor(pm, 2));
      pm = fmaxf(pm, __shfl_xor(pm, 4));
      pm = fmaxf(pm, __shfl_xor(pm, 8));
      float mn = fmaxf(mi[r], pm);
      float a = __expf(mi[r] - mn);
      mi[r] = mn;
      float rs = 0.f;
#pragma unroll
      for (int c = 0; c < 4; ++c) { s[r][c] = __expf(s[r][c] - mn); rs += s[r][c]; }
      rs += __shfl_xor(rs, 1);
      rs += __shfl_xor(rs, 2);
      rs += __shfl_xor(rs, 4);
      rs += __shfl_xor(rs, 8);
      li[r] = li[r] * a + rs;
#pragma unroll
      for (int c = 0; c < 4; ++c) acc[r][c] *= a;
    }
    __syncthreads();  // all S-phase LDS reads complete

    // write V (into K buffer) and P (into table buffer)
#pragma unroll
    for (int it = 0; it < 4; ++it) {
      int f4 = it * 256 + t;
      int j = f4 >> 4;
      int d4 = (f4 & 15) << 2;
      *(float4*)&kvs[j][d4] = vreg[it];
    }
#pragma unroll
    for (int r = 0; r < 4; ++r)
#pragma unroll
      for (int c = 0; c < 4; ++c) tsps[g + 16 * r][tx + 16 * c] = s[r][c];
    __syncthreads();

    // acc += P @ V
#pragma unroll 4
    for (int j0 = 0; j0 < 64; j0 += 4) {
      float pv[4][4];
#pragma unroll
      for (int r = 0; r < 4; ++r) *(float4*)pv[r] = *(const float4*)&tsps[g + 16 * r][j0];
#pragma unroll
      for (int e = 0; e < 4; ++e) {
        float vb[4];
#pragma unroll
        for (int c = 0; c < 4; ++c) vb[c] = kvs[j0 + e][tx + 16 * c];
#pragma unroll
        for (int r = 0; r < 4; ++r)
#pragma unroll
          for (int c = 0; c < 4; ++c) acc[r][c] += pv[r][e] * vb[c];
      }
    }
  }

  // write attn = acc / li
#pragma unroll
  for (int r = 0; r < 4; ++r) {
    float inv = 1.0f / li[r];
#pragma unroll
    for (int c = 0; c < 4; ++c)
      attn[(size_t)((n0 + g + 16 * r) * BZ + z) * DM + h * DH + tx + 16 * c] = acc[r][c] * inv;
  }
}

// ---------------- launch ----------------
extern "C" void kernel_launch(void* const* d_in, const int* in_sizes, int n_in,
                              void* d_out, int out_size, void* d_ws, size_t ws_size,
                              hipStream_t stream) {
  const float* x_q   = (const float*)d_in[0];
  const float* x_kv  = (const float*)d_in[1];
  const float* to_q  = (const float*)d_in[2];
  const float* to_kv = (const float*)d_in[3];
  const float* fpe   = (const float*)d_in[4];
  const float* to_o  = (const float*)d_in[5];
  float* out = (float*)d_out;

  float* ws = (float*)d_ws;
  float* qbuf   = ws;                           // 4096*1024
  float* kvbuf  = qbuf + (size_t)4096 * 1024;   // 4096*2048
  float* tabbuf = kvbuf + (size_t)4096 * 2048;  // 4095*1024 (rows >= R0TAB valid)
  float* scbuf  = tabbuf + (size_t)4096 * 1024; // sincos first, attn later (aliased)

  // 1. sincos (reachable rows only)
  {
    int nel = (RTAB - R0TAB) * DM;
    sincos_kernel<<<dim3((nel + 255) / 256), dim3(256), 0, stream>>>(scbuf);
  }
  // 2. table = sincos @ fpe^T  (rows R0TAB..4094)
  gemm_nt<<<dim3(1024 / 128, (RTAB - R0TAB + 127) / 128), dim3(256), 0, stream>>>(
      scbuf + (size_t)R0TAB * DM, fpe, tabbuf + (size_t)R0TAB * DM, RTAB - R0TAB, 1024, 1024);
  // 3. q = x_q @ to_q^T
  gemm_nt<<<dim3(1024 / 128, 4096 / 128), dim3(256), 0, stream>>>(
      x_q, to_q, qbuf, 4096, 1024, 1024);
  // 4. kv = x_kv @ to_kv^T
  gemm_nt<<<dim3(2048 / 128, 4096 / 128), dim3(256), 0, stream>>>(
      x_kv, to_kv, kvbuf, 4096, 2048, 1024);
  // 5. fused attention
  attn_kernel<<<dim3(NQ / 64, BZ, NH), dim3(256), 0, stream>>>(qbuf, kvbuf, tabbuf, scbuf);
  // 6. out = attn @ to_o^T
  gemm_nt<<<dim3(1024 / 128, 4096 / 128), dim3(256), 0, stream>>>(
      scbuf, to_o, out, 4096, 1024, 1024);
}

// Round 3
// 965.650 us; speedup vs baseline: 3.3154x; 1.8191x over previous
//
#include <hip/hip_runtime.h>
#include <math.h>

#define NQ 2048
#define MKV 2048
#define BZ 2
#define DM 1024
#define NH 16
#define DH 64
#define RTAB 4095  /* NQ + MKV - 1 */
#define R0TAB 1984 /* lowest table row reachable under causal mask */

typedef __bf16 bf16x8 __attribute__((ext_vector_type(8)));
typedef float f32x4 __attribute__((ext_vector_type(4)));

union BF8 { bf16x8 v; unsigned short u[8]; };

__device__ inline unsigned short f2bf(float x) {
  union { float f; unsigned u; } v; v.f = x;
  unsigned r = (v.u + 0x7FFFu + ((v.u >> 16) & 1u)) >> 16;
  return (unsigned short)r;
}
__device__ inline float bf2f(unsigned short h) {
  union { unsigned u; float f; } v; v.u = ((unsigned)h) << 16; return v.f;
}

#define SWZ(r, b) ((b) ^ (((r) & 7) << 4))

// ---------------- sincos table (rows R0TAB..4094 only) ----------------
__global__ __launch_bounds__(256) void sincos_kernel(float* __restrict__ sc) {
  int idx = blockIdx.x * 256 + threadIdx.x;
  if (idx >= (RTAB - R0TAB) * DM) return;
  int r = R0TAB + idx / DM;
  int b = idx - (r - R0TAB) * DM;
  int i = (b < DM / 2) ? b : (b - DM / 2);
  double fr = exp((double)i * (-9.210340371976184 / 512.0));
  float rr = (float)(r - (MKV - 1));
  float ph = rr * (float)fr;
  sc[(size_t)r * DM + b] = (b < DM / 2) ? sinf(ph) : cosf(ph);
}

// ---------------- NT GEMM: C[M][N] = sum_k A[M][K] * B[N][K] ----------------
__global__ __launch_bounds__(256) void gemm_nt(const float* __restrict__ A,
                                               const float* __restrict__ B,
                                               float* __restrict__ C,
                                               int M, int N, int K) {
  __shared__ float As[128][20];
  __shared__ float Bs[128][20];
  const int t = threadIdx.x;
  const int g = t >> 4;
  const int tx = t & 15;
  const int row0 = blockIdx.y * 128;
  const int col0 = blockIdx.x * 128;
  const int lr = t >> 2;
  const int lk = (t & 3) << 2;
  float acc[8][8] = {};
  for (int k0 = 0; k0 < K; k0 += 16) {
#pragma unroll
    for (int half = 0; half < 2; ++half) {
      int r = half * 64 + lr;
      float4 av = make_float4(0.f, 0.f, 0.f, 0.f);
      if (row0 + r < M) av = *(const float4*)(A + (size_t)(row0 + r) * K + k0 + lk);
      float4 bv = *(const float4*)(B + (size_t)(col0 + r) * K + k0 + lk);
      *(float4*)&As[r][lk] = av;
      *(float4*)&Bs[r][lk] = bv;
    }
    __syncthreads();
#pragma unroll
    for (int kq = 0; kq < 16; kq += 2) {
      float2 a2[8], b2[8];
#pragma unroll
      for (int r = 0; r < 8; ++r) a2[r] = *(const float2*)&As[g + 16 * r][kq];
#pragma unroll
      for (int c = 0; c < 8; ++c) b2[c] = *(const float2*)&Bs[tx + 16 * c][kq];
#pragma unroll
      for (int r = 0; r < 8; ++r)
#pragma unroll
        for (int c = 0; c < 8; ++c) {
          acc[r][c] += a2[r].x * b2[c].x;
          acc[r][c] += a2[r].y * b2[c].y;
        }
    }
    __syncthreads();
  }
#pragma unroll
  for (int r = 0; r < 8; ++r) {
    int row = row0 + g + 16 * r;
    if (row < M) {
#pragma unroll
      for (int c = 0; c < 8; ++c)
        C[(size_t)row * N + col0 + tx + 16 * c] = acc[r][c];
    }
  }
}

// ---------------- MFMA fused causal attention with relative positions ----------------
// Split-bf16 (hi/lo) QK^T and QT^T for fp32-grade logits; bf16 PV.
__global__ __launch_bounds__(256, 2) void attn_kernel(const float* __restrict__ q,
                                                      const float* __restrict__ kv,
                                                      const float* __restrict__ tab,
                                                      float* __restrict__ attn) {
  const int qb = (int)gridDim.x - 1 - (int)blockIdx.x;  // heavy blocks first
  const int z = blockIdx.y;
  const int h = blockIdx.z;
  const int n0 = qb * 64;

  __shared__ __align__(16) char sKhi[8192];   // K hi bf16 [64][64], swizzled
  __shared__ __align__(16) char sKlo[8192];   // K lo
  __shared__ __align__(16) char sT[32768];    // Thi [0,16K) + Tlo [16K,32K), 128 rows; later per-wave PL f32
  __shared__ __align__(16) char sVT[8192];    // V^T bf16 [64 dv][64 m], swizzled
  __shared__ __align__(16) char sP[8192];     // P bf16 [64 n][64 m], swizzled

  const int t = threadIdx.x;
  const int w = t >> 6;
  const int lane = t & 63;
  const int lo = lane & 15;
  const int hi = lane >> 4;

  // ---- Q fragments: A-layout row n = 16w+lo, k d = 32ks+8hi+e; split hi/lo
  bf16x8 qh[2], ql[2];
  {
    const float* qrow = q + (size_t)((n0 + 16 * w + lo) * BZ + z) * DM + h * DH;
#pragma unroll
    for (int ks = 0; ks < 2; ++ks) {
      float f[8];
      *(float4*)(f) = *(const float4*)(qrow + 32 * ks + 8 * hi);
      *(float4*)(f + 4) = *(const float4*)(qrow + 32 * ks + 8 * hi + 4);
      BF8 H, L;
#pragma unroll
      for (int e = 0; e < 8; ++e) {
        unsigned short hb = f2bf(f[e]);
        H.u[e] = hb;
        L.u[e] = f2bf(f[e] - bf2f(hb));
      }
      qh[ks] = H.v;
      ql[ks] = L.v;
    }
  }

  f32x4 accO[4];
#pragma unroll
  for (int f = 0; f < 4; ++f) accO[f] = (f32x4){0.f, 0.f, 0.f, 0.f};
  float mi[4], li[4];
#pragma unroll
  for (int qq = 0; qq < 4; ++qq) { mi[qq] = -1e30f; li[qq] = 0.f; }

  for (int mt = 0; mt <= qb; ++mt) {
    const int m0 = mt * 64;
    const int Wb = n0 - m0 + R0TAB;
    __syncthreads();  // prior tile's LDS reads complete before restaging

    // ---- stage K (hi/lo) and V^T
#pragma unroll
    for (int it = 0; it < 4; ++it) {
      int f4 = it * 256 + t;
      int j = f4 >> 4;
      int d4 = (f4 & 15) << 2;
      const float* base = kv + (size_t)((m0 + j) * BZ + z) * (NH * 2 * DH) + h * (2 * DH);
      float4 kk = *(const float4*)(base + d4);
      float4 vv = *(const float4*)(base + DH + d4);
      float kf[4] = {kk.x, kk.y, kk.z, kk.w};
      float vf[4] = {vv.x, vv.y, vv.z, vv.w};
      ushort4 khw, klw;
      unsigned short* kh = (unsigned short*)&khw;
      unsigned short* kl = (unsigned short*)&klw;
#pragma unroll
      for (int i = 0; i < 4; ++i) {
        unsigned short hb = f2bf(kf[i]);
        kh[i] = hb;
        kl[i] = f2bf(kf[i] - bf2f(hb));
      }
      int kb = SWZ(j, j * 128 + d4 * 2);
      *(ushort4*)(sKhi + kb) = khw;
      *(ushort4*)(sKlo + kb) = klw;
#pragma unroll
      for (int i = 0; i < 4; ++i) {
        int dv = d4 + i;
        *(unsigned short*)(sVT + SWZ(dv, dv * 128 + j * 2)) = f2bf(vf[i]);
      }
    }
    // ---- stage T window (128 rows; row 127 clamped) hi/lo
#pragma unroll
    for (int it = 0; it < 8; ++it) {
      int f4 = it * 256 + t;
      int rr = f4 >> 4;
      int rc = rr < 127 ? rr : 126;
      int d4 = (f4 & 15) << 2;
      float4 tt = *(const float4*)(tab + (size_t)(Wb + rc) * DM + h * DH + d4);
      float tf[4] = {tt.x, tt.y, tt.z, tt.w};
      ushort4 thw, tlw;
      unsigned short* th = (unsigned short*)&thw;
      unsigned short* tl = (unsigned short*)&tlw;
#pragma unroll
      for (int i = 0; i < 4; ++i) {
        unsigned short hb = f2bf(tf[i]);
        th[i] = hb;
        tl[i] = f2bf(tf[i] - bf2f(hb));
      }
      int tb = SWZ(rr, rr * 128 + d4 * 2);
      *(ushort4*)(sT + tb) = thw;
      *(ushort4*)(sT + 16384 + tb) = tlw;
    }
    __syncthreads();

    // ---- S = QK^T (content) and PL = QT^T (position), split-bf16 MFMA
    f32x4 accS[4], accPL[5];
#pragma unroll
    for (int f = 0; f < 4; ++f) accS[f] = (f32x4){0.f, 0.f, 0.f, 0.f};
#pragma unroll
    for (int f = 0; f < 5; ++f) accPL[f] = (f32x4){0.f, 0.f, 0.f, 0.f};
#pragma unroll
    for (int ks = 0; ks < 2; ++ks) {
#pragma unroll
      for (int fm = 0; fm < 4; ++fm) {
        int rb = SWZ(lo, (16 * fm + lo) * 128 + (32 * ks + 8 * hi) * 2);
        bf16x8 kh = *(const bf16x8*)(sKhi + rb);
        bf16x8 kl = *(const bf16x8*)(sKlo + rb);
        accS[fm] = __builtin_amdgcn_mfma_f32_16x16x32_bf16(qh[ks], kh, accS[fm], 0, 0, 0);
        accS[fm] = __builtin_amdgcn_mfma_f32_16x16x32_bf16(qh[ks], kl, accS[fm], 0, 0, 0);
        accS[fm] = __builtin_amdgcn_mfma_f32_16x16x32_bf16(ql[ks], kh, accS[fm], 0, 0, 0);
      }
#pragma unroll
      for (int fr = 0; fr < 5; ++fr) {
        int r = 16 * (w + fr) + lo;
        int rb = SWZ(lo, r * 128 + (32 * ks + 8 * hi) * 2);
        bf16x8 th = *(const bf16x8*)(sT + rb);
        bf16x8 tl = *(const bf16x8*)(sT + 16384 + rb);
        accPL[fr] = __builtin_amdgcn_mfma_f32_16x16x32_bf16(qh[ks], th, accPL[fr], 0, 0, 0);
        accPL[fr] = __builtin_amdgcn_mfma_f32_16x16x32_bf16(qh[ks], tl, accPL[fr], 0, 0, 0);
        accPL[fr] = __builtin_amdgcn_mfma_f32_16x16x32_bf16(ql[ks], th, accPL[fr], 0, 0, 0);
      }
    }
    __syncthreads();  // all T reads done before PL overwrites sT

    // ---- PL bounce to per-wave LDS region (aliases sT), then diagonal gather
    float* plb = (float*)sT + (size_t)w * 16 * 84;
#pragma unroll
    for (int fr = 0; fr < 5; ++fr)
#pragma unroll
      for (int qq = 0; qq < 4; ++qq)
        plb[(4 * hi + qq) * 84 + 16 * fr + lo] = accPL[fr][qq];
#pragma unroll
    for (int fm = 0; fm < 4; ++fm)
#pragma unroll
      for (int qq = 0; qq < 4; ++qq) {
        int rn = 4 * hi + qq + 63 - 16 * fm - lo;  // in [0,78]
        accS[fm][qq] += plb[(4 * hi + qq) * 84 + rn];
      }

    if (mt == qb) {  // diagonal tile: mask m > n
#pragma unroll
      for (int fm = 0; fm < 4; ++fm)
#pragma unroll
        for (int qq = 0; qq < 4; ++qq)
          if (16 * fm + lo > 16 * w + 4 * hi + qq) accS[fm][qq] = -1e30f;
    }

    // ---- online softmax in registers (rows live in lanes sharing hi)
#pragma unroll
    for (int qq = 0; qq < 4; ++qq) {
      float pm = fmaxf(fmaxf(accS[0][qq], accS[1][qq]), fmaxf(accS[2][qq], accS[3][qq]));
      pm = fmaxf(pm, __shfl_xor(pm, 1));
      pm = fmaxf(pm, __shfl_xor(pm, 2));
      pm = fmaxf(pm, __shfl_xor(pm, 4));
      pm = fmaxf(pm, __shfl_xor(pm, 8));
      float mn = fmaxf(mi[qq], pm);
      float a = __expf(mi[qq] - mn);
      mi[qq] = mn;
      float rs = 0.f;
#pragma unroll
      for (int fm = 0; fm < 4; ++fm) {
        float p = __expf(accS[fm][qq] - mn);
        accS[fm][qq] = p;
        rs += p;
      }
      rs += __shfl_xor(rs, 1);
      rs += __shfl_xor(rs, 2);
      rs += __shfl_xor(rs, 4);
      rs += __shfl_xor(rs, 8);
      li[qq] = li[qq] * a + rs;
#pragma unroll
      for (int f = 0; f < 4; ++f) accO[f][qq] *= a;
    }

    // ---- P -> LDS bf16 (wave-local rows; no barrier needed)
#pragma unroll
    for (int fm = 0; fm < 4; ++fm)
#pragma unroll
      for (int qq = 0; qq < 4; ++qq) {
        int row = 16 * w + 4 * hi + qq;
        *(unsigned short*)(sP + SWZ(4 * hi + qq, row * 128 + (16 * fm + lo) * 2)) =
            f2bf(accS[fm][qq]);
      }

    // ---- PV: accO += P @ V
#pragma unroll
    for (int ks = 0; ks < 2; ++ks) {
      int ab = SWZ(lo, (16 * w + lo) * 128 + (32 * ks + 8 * hi) * 2);
      bf16x8 pa = *(const bf16x8*)(sP + ab);
#pragma unroll
      for (int fv = 0; fv < 4; ++fv) {
        int vb = SWZ(lo, (16 * fv + lo) * 128 + (32 * ks + 8 * hi) * 2);
        bf16x8 vv = *(const bf16x8*)(sVT + vb);
        accO[fv] = __builtin_amdgcn_mfma_f32_16x16x32_bf16(pa, vv, accO[fv], 0, 0, 0);
      }
    }
  }

  // ---- epilogue: attn = accO / li
#pragma unroll
  for (int qq = 0; qq < 4; ++qq) {
    float inv = 1.0f / li[qq];
    int n = n0 + 16 * w + 4 * hi + qq;
#pragma unroll
    for (int fv = 0; fv < 4; ++fv)
      attn[(size_t)(n * BZ + z) * DM + h * DH + 16 * fv + lo] = accO[fv][qq] * inv;
  }
}

// ---------------- launch ----------------
extern "C" void kernel_launch(void* const* d_in, const int* in_sizes, int n_in,
                              void* d_out, int out_size, void* d_ws, size_t ws_size,
                              hipStream_t stream) {
  const float* x_q   = (const float*)d_in[0];
  const float* x_kv  = (const float*)d_in[1];
  const float* to_q  = (const float*)d_in[2];
  const float* to_kv = (const float*)d_in[3];
  const float* fpe   = (const float*)d_in[4];
  const float* to_o  = (const float*)d_in[5];
  float* out = (float*)d_out;

  float* ws = (float*)d_ws;
  float* qbuf   = ws;                           // 4096*1024
  float* kvbuf  = qbuf + (size_t)4096 * 1024;   // 4096*2048
  float* tabbuf = kvbuf + (size_t)4096 * 2048;  // 4095*1024 (rows >= R0TAB valid)
  float* scbuf  = tabbuf + (size_t)4096 * 1024; // sincos first, attn later (aliased)

  {
    int nel = (RTAB - R0TAB) * DM;
    sincos_kernel<<<dim3((nel + 255) / 256), dim3(256), 0, stream>>>(scbuf);
  }
  gemm_nt<<<dim3(1024 / 128, (RTAB - R0TAB + 127) / 128), dim3(256), 0, stream>>>(
      scbuf + (size_t)R0TAB * DM, fpe, tabbuf + (size_t)R0TAB * DM, RTAB - R0TAB, 1024, 1024);
  gemm_nt<<<dim3(1024 / 128, 4096 / 128), dim3(256), 0, stream>>>(
      x_q, to_q, qbuf, 4096, 1024, 1024);
  gemm_nt<<<dim3(2048 / 128, 4096 / 128), dim3(256), 0, stream>>>(
      x_kv, to_kv, kvbuf, 4096, 2048, 1024);
  attn_kernel<<<dim3(NQ / 64, BZ, NH), dim3(256), 0, stream>>>(qbuf, kvbuf, tabbuf, scbuf);
  gemm_nt<<<dim3(1024 / 128, 4096 / 128), dim3(256), 0, stream>>>(
      scbuf, to_o, out, 4096, 1024, 1024);
}

// Round 4
// 459.086 us; speedup vs baseline: 6.9737x; 2.1034x over previous
//
#include <hip/hip_runtime.h>
#include <math.h>

#define NQ 2048
#define MKV 2048
#define BZ 2
#define DM 1024
#define NH 16
#define DH 64
#define RTAB 4095  /* NQ + MKV - 1 */
#define R0TAB 1984 /* lowest table row reachable under causal mask */
#define MTAB (RTAB - R0TAB) /* 2111 */

typedef __bf16 bf16x8 __attribute__((ext_vector_type(8)));
typedef float f32x4 __attribute__((ext_vector_type(4)));

__device__ inline unsigned short f2bf(float x) {
  union { float f; unsigned u; } v; v.f = x;
  unsigned r = (v.u + 0x7FFFu + ((v.u >> 16) & 1u)) >> 16;
  return (unsigned short)r;
}
__device__ inline float bf2f(unsigned short h) {
  union { unsigned u; float f; } v; v.u = ((unsigned)h) << 16; return v.f;
}

#define SWZ(r, b) ((b) ^ (((r) & 7) << 4))

__device__ inline void gload_lds16(const void* g, void* l) {
  __builtin_amdgcn_global_load_lds((const __attribute__((address_space(1))) void*)g,
                                   (__attribute__((address_space(3))) void*)l, 16, 0, 0);
}

// ---------------- fp32 -> (hi,lo) bf16 split planes ----------------
__global__ __launch_bounds__(256) void split_kernel(const float* __restrict__ in,
                                                    unsigned short* __restrict__ hi,
                                                    unsigned short* __restrict__ lo,
                                                    int n4) {
  int i = blockIdx.x * 256 + threadIdx.x;
  if (i >= n4) return;
  float4 v = ((const float4*)in)[i];
  float f[4] = {v.x, v.y, v.z, v.w};
  ushort4 h4, l4;
  unsigned short* hp = (unsigned short*)&h4;
  unsigned short* lp = (unsigned short*)&l4;
#pragma unroll
  for (int e = 0; e < 4; ++e) {
    unsigned short hb = f2bf(f[e]);
    hp[e] = hb;
    lp[e] = f2bf(f[e] - bf2f(hb));
  }
  ((ushort4*)hi)[i] = h4;
  ((ushort4*)lo)[i] = l4;
}

// ---------------- sincos table, split planes (rows R0TAB..4094 as 0..2110) ----------------
__global__ __launch_bounds__(256) void sincos_kernel(unsigned short* __restrict__ hi,
                                                     unsigned short* __restrict__ lo) {
  int idx = blockIdx.x * 256 + threadIdx.x;
  if (idx >= MTAB * DM) return;
  int r = idx / DM;  // 0..2110 -> table row R0TAB + r
  int b = idx - r * DM;
  int i = (b < DM / 2) ? b : (b - DM / 2);
  double fr = exp((double)i * (-9.210340371976184 / 512.0));
  float rr = (float)(R0TAB + r - (MKV - 1));
  float ph = rr * (float)fr;
  float val = (b < DM / 2) ? sinf(ph) : cosf(ph);
  unsigned short hb = f2bf(val);
  hi[idx] = hb;
  lo[idx] = f2bf(val - bf2f(hb));
}

// ---------------- split-bf16 MFMA NT GEMM ----------------
// C[M][N] = sum_k (Ahi+Alo)[M][K] * (Bhi+Blo)[N][K]  (lo*lo dropped)
// 128x128 tile, BK=64, 4 waves (2x2), 16x16x32 MFMA, global_load_lds staging
// with pre-swizzled source (read swizzle: 16B-chunk ^= row&7).
template <int SPLIT_OUT>
__global__ __launch_bounds__(256, 2) void gemm_bf16s(
    const unsigned short* __restrict__ Ahi, const unsigned short* __restrict__ Alo,
    const unsigned short* __restrict__ Bhi, const unsigned short* __restrict__ Blo,
    float* __restrict__ Cf, unsigned short* __restrict__ Chi, unsigned short* __restrict__ Clo,
    int M, int N, int K) {
  __shared__ char lds[65536];
  char* sAh = lds;
  char* sAl = lds + 16384;
  char* sBh = lds + 32768;
  char* sBl = lds + 49152;
  const int t = threadIdx.x;
  const int w = t >> 6;
  const int lane = t & 63;
  const int lo = lane & 15;
  const int hi = lane >> 4;
  const int wm = w >> 1, wn = w & 1;
  const int row0 = blockIdx.y * 128;
  const int col0 = blockIdx.x * 128;

  f32x4 acc[4][4];
#pragma unroll
  for (int a = 0; a < 4; ++a)
#pragma unroll
    for (int b = 0; b < 4; ++b) acc[a][b] = (f32x4){0.f, 0.f, 0.f, 0.f};

  for (int k0 = 0; k0 < K; k0 += 64) {
#pragma unroll
    for (int i = 0; i < 4; ++i) {
      int L = i * 4096 + t * 16;
      int r = L >> 7;
      int c16 = (L >> 4) & 7;
      int g16 = c16 ^ (r & 7);
      int ra = row0 + r;
      if (ra >= M) ra = M - 1;
      int rb = col0 + r;
      const char* gah = (const char*)(Ahi + (size_t)ra * K + k0) + g16 * 16;
      const char* gal = (const char*)(Alo + (size_t)ra * K + k0) + g16 * 16;
      const char* gbh = (const char*)(Bhi + (size_t)rb * K + k0) + g16 * 16;
      const char* gbl = (const char*)(Blo + (size_t)rb * K + k0) + g16 * 16;
      gload_lds16(gah, sAh + L);
      gload_lds16(gal, sAl + L);
      gload_lds16(gbh, sBh + L);
      gload_lds16(gbl, sBl + L);
    }
    __syncthreads();
#pragma unroll
    for (int ks = 0; ks < 2; ++ks) {
      bf16x8 ah[4], al[4], bh[4], bl[4];
#pragma unroll
      for (int f = 0; f < 4; ++f) {
        int rA = wm * 64 + 16 * f + lo;
        int offA = rA * 128 + (((4 * ks + hi) ^ (rA & 7)) << 4);
        ah[f] = *(const bf16x8*)(sAh + offA);
        al[f] = *(const bf16x8*)(sAl + offA);
        int rB = wn * 64 + 16 * f + lo;
        int offB = rB * 128 + (((4 * ks + hi) ^ (rB & 7)) << 4);
        bh[f] = *(const bf16x8*)(sBh + offB);
        bl[f] = *(const bf16x8*)(sBl + offB);
      }
#pragma unroll
      for (int fm = 0; fm < 4; ++fm)
#pragma unroll
        for (int fn = 0; fn < 4; ++fn) {
          acc[fm][fn] = __builtin_amdgcn_mfma_f32_16x16x32_bf16(ah[fm], bh[fn], acc[fm][fn], 0, 0, 0);
          acc[fm][fn] = __builtin_amdgcn_mfma_f32_16x16x32_bf16(ah[fm], bl[fn], acc[fm][fn], 0, 0, 0);
          acc[fm][fn] = __builtin_amdgcn_mfma_f32_16x16x32_bf16(al[fm], bh[fn], acc[fm][fn], 0, 0, 0);
        }
    }
    __syncthreads();
  }
  // epilogue
#pragma unroll
  for (int fm = 0; fm < 4; ++fm)
#pragma unroll
    for (int qq = 0; qq < 4; ++qq) {
      int row = row0 + wm * 64 + 16 * fm + 4 * hi + qq;
      if (row < M) {
#pragma unroll
        for (int fn = 0; fn < 4; ++fn) {
          int col = col0 + wn * 64 + 16 * fn + lo;
          float v = acc[fm][fn][qq];
          if (SPLIT_OUT) {
            unsigned short hb = f2bf(v);
            Chi[(size_t)row * N + col] = hb;
            Clo[(size_t)row * N + col] = f2bf(v - bf2f(hb));
          } else {
            Cf[(size_t)row * N + col] = v;
          }
        }
      }
    }
}

// ---------------- MFMA fused causal attention, split-bf16 inputs ----------------
union U8 { uint4 q; unsigned short u[8]; };

__global__ __launch_bounds__(256, 2) void attn_kernel(
    const unsigned short* __restrict__ qhi, const unsigned short* __restrict__ qlo,
    const unsigned short* __restrict__ kvhi, const unsigned short* __restrict__ kvlo,
    const unsigned short* __restrict__ tabhi, const unsigned short* __restrict__ tablo,
    unsigned short* __restrict__ ohi, unsigned short* __restrict__ olo) {
  const int qb = (int)gridDim.x - 1 - (int)blockIdx.x;  // heavy blocks first
  const int z = blockIdx.y;
  const int h = blockIdx.z;
  const int n0 = qb * 64;

  __shared__ __align__(16) char sKhi[8192];   // K hi bf16 [64][64], swizzled
  __shared__ __align__(16) char sKlo[8192];   // K lo
  __shared__ __align__(16) char sT[32768];    // Thi [0,16K) + Tlo [16K,32K); later per-wave PL f32
  __shared__ __align__(16) char sVT[8192];    // V^T bf16 [64 dv][64 m], swizzled
  __shared__ __align__(16) char sP[8192];     // P bf16 [64 n][64 m], swizzled

  const int t = threadIdx.x;
  const int w = t >> 6;
  const int lane = t & 63;
  const int lo = lane & 15;
  const int hi = lane >> 4;

  // ---- Q fragments straight from split planes
  bf16x8 qh[2], ql[2];
  {
    size_t qoff = (size_t)((n0 + 16 * w + lo) * BZ + z) * DM + h * DH;
#pragma unroll
    for (int ks = 0; ks < 2; ++ks) {
      qh[ks] = *(const bf16x8*)(qhi + qoff + 32 * ks + 8 * hi);
      ql[ks] = *(const bf16x8*)(qlo + qoff + 32 * ks + 8 * hi);
    }
  }

  f32x4 accO[4];
#pragma unroll
  for (int f = 0; f < 4; ++f) accO[f] = (f32x4){0.f, 0.f, 0.f, 0.f};
  float mi[4], li[4];
#pragma unroll
  for (int qq = 0; qq < 4; ++qq) { mi[qq] = -1e30f; li[qq] = 0.f; }

  for (int mt = 0; mt <= qb; ++mt) {
    const int m0 = mt * 64;
    const int Wb = n0 - m0 + R0TAB;
    __syncthreads();  // prior tile's LDS reads complete before restaging

    // ---- stage K (hi/lo) and V^T (hi only)
#pragma unroll
    for (int it = 0; it < 2; ++it) {
      int f = it * 256 + t;     // 0..511
      int j = f >> 3;           // 0..63
      int d8 = (f & 7) << 3;    // 0,8,..,56
      size_t gb = (size_t)((m0 + j) * BZ + z) * (NH * 2 * DH) + h * (2 * DH);
      uint4 kh = *(const uint4*)(kvhi + gb + d8);
      uint4 kl = *(const uint4*)(kvlo + gb + d8);
      int kb = SWZ(j, j * 128 + d8 * 2);
      *(uint4*)(sKhi + kb) = kh;
      *(uint4*)(sKlo + kb) = kl;
      U8 vh;
      vh.q = *(const uint4*)(kvhi + gb + DH + d8);
#pragma unroll
      for (int e = 0; e < 8; ++e) {
        int dv = d8 + e;
        *(unsigned short*)(sVT + SWZ(dv, dv * 128 + j * 2)) = vh.u[e];
      }
    }
    // ---- stage T window (128 rows; row 127 clamped)
#pragma unroll
    for (int it = 0; it < 4; ++it) {
      int f = it * 256 + t;     // 0..1023
      int rr = f >> 3;          // 0..127
      int rc = rr < 127 ? rr : 126;
      int d8 = (f & 7) << 3;
      size_t gb = (size_t)(Wb + rc) * DM + h * DH + d8;
      uint4 th = *(const uint4*)(tabhi + gb);
      uint4 tl = *(const uint4*)(tablo + gb);
      int tb = SWZ(rr, rr * 128 + d8 * 2);
      *(uint4*)(sT + tb) = th;
      *(uint4*)(sT + 16384 + tb) = tl;
    }
    __syncthreads();

    // ---- S = QK^T and PL = QT^T, split-bf16 MFMA
    f32x4 accS[4], accPL[5];
#pragma unroll
    for (int f = 0; f < 4; ++f) accS[f] = (f32x4){0.f, 0.f, 0.f, 0.f};
#pragma unroll
    for (int f = 0; f < 5; ++f) accPL[f] = (f32x4){0.f, 0.f, 0.f, 0.f};
#pragma unroll
    for (int ks = 0; ks < 2; ++ks) {
#pragma unroll
      for (int fm = 0; fm < 4; ++fm) {
        int rb = SWZ(lo, (16 * fm + lo) * 128 + (32 * ks + 8 * hi) * 2);
        bf16x8 kh = *(const bf16x8*)(sKhi + rb);
        bf16x8 kl = *(const bf16x8*)(sKlo + rb);
        accS[fm] = __builtin_amdgcn_mfma_f32_16x16x32_bf16(qh[ks], kh, accS[fm], 0, 0, 0);
        accS[fm] = __builtin_amdgcn_mfma_f32_16x16x32_bf16(qh[ks], kl, accS[fm], 0, 0, 0);
        accS[fm] = __builtin_amdgcn_mfma_f32_16x16x32_bf16(ql[ks], kh, accS[fm], 0, 0, 0);
      }
#pragma unroll
      for (int fr = 0; fr < 5; ++fr) {
        int r = 16 * (w + fr) + lo;
        int rb = SWZ(lo, r * 128 + (32 * ks + 8 * hi) * 2);
        bf16x8 th = *(const bf16x8*)(sT + rb);
        bf16x8 tl = *(const bf16x8*)(sT + 16384 + rb);
        accPL[fr] = __builtin_amdgcn_mfma_f32_16x16x32_bf16(qh[ks], th, accPL[fr], 0, 0, 0);
        accPL[fr] = __builtin_amdgcn_mfma_f32_16x16x32_bf16(qh[ks], tl, accPL[fr], 0, 0, 0);
        accPL[fr] = __builtin_amdgcn_mfma_f32_16x16x32_bf16(ql[ks], th, accPL[fr], 0, 0, 0);
      }
    }
    __syncthreads();  // all T reads done before PL overwrites sT

    // ---- PL bounce to per-wave LDS region (aliases sT), then diagonal gather
    float* plb = (float*)sT + (size_t)w * 16 * 84;
#pragma unroll
    for (int fr = 0; fr < 5; ++fr)
#pragma unroll
      for (int qq = 0; qq < 4; ++qq)
        plb[(4 * hi + qq) * 84 + 16 * fr + lo] = accPL[fr][qq];
#pragma unroll
    for (int fm = 0; fm < 4; ++fm)
#pragma unroll
      for (int qq = 0; qq < 4; ++qq) {
        int rn = 4 * hi + qq + 63 - 16 * fm - lo;  // in [0,78]
        accS[fm][qq] += plb[(4 * hi + qq) * 84 + rn];
      }

    if (mt == qb) {  // diagonal tile: mask m > n
#pragma unroll
      for (int fm = 0; fm < 4; ++fm)
#pragma unroll
        for (int qq = 0; qq < 4; ++qq)
          if (16 * fm + lo > 16 * w + 4 * hi + qq) accS[fm][qq] = -1e30f;
    }

    // ---- online softmax in registers
#pragma unroll
    for (int qq = 0; qq < 4; ++qq) {
      float pm = fmaxf(fmaxf(accS[0][qq], accS[1][qq]), fmaxf(accS[2][qq], accS[3][qq]));
      pm = fmaxf(pm, __shfl_xor(pm, 1));
      pm = fmaxf(pm, __shfl_xor(pm, 2));
      pm = fmaxf(pm, __shfl_xor(pm, 4));
      pm = fmaxf(pm, __shfl_xor(pm, 8));
      float mn = fmaxf(mi[qq], pm);
      float a = __expf(mi[qq] - mn);
      mi[qq] = mn;
      float rs = 0.f;
#pragma unroll
      for (int fm = 0; fm < 4; ++fm) {
        float p = __expf(accS[fm][qq] - mn);
        accS[fm][qq] = p;
        rs += p;
      }
      rs += __shfl_xor(rs, 1);
      rs += __shfl_xor(rs, 2);
      rs += __shfl_xor(rs, 4);
      rs += __shfl_xor(rs, 8);
      li[qq] = li[qq] * a + rs;
#pragma unroll
      for (int f = 0; f < 4; ++f) accO[f][qq] *= a;
    }

    // ---- P -> LDS bf16 (wave-local rows)
#pragma unroll
    for (int fm = 0; fm < 4; ++fm)
#pragma unroll
      for (int qq = 0; qq < 4; ++qq) {
        int row = 16 * w + 4 * hi + qq;
        *(unsigned short*)(sP + SWZ(4 * hi + qq, row * 128 + (16 * fm + lo) * 2)) =
            f2bf(accS[fm][qq]);
      }

    // ---- PV: accO += P @ V
#pragma unroll
    for (int ks = 0; ks < 2; ++ks) {
      int ab = SWZ(lo, (16 * w + lo) * 128 + (32 * ks + 8 * hi) * 2);
      bf16x8 pa = *(const bf16x8*)(sP + ab);
#pragma unroll
      for (int fv = 0; fv < 4; ++fv) {
        int vb = SWZ(lo, (16 * fv + lo) * 128 + (32 * ks + 8 * hi) * 2);
        bf16x8 vv = *(const bf16x8*)(sVT + vb);
        accO[fv] = __builtin_amdgcn_mfma_f32_16x16x32_bf16(pa, vv, accO[fv], 0, 0, 0);
      }
    }
  }

  // ---- epilogue: attn = accO / li, written as split planes
#pragma unroll
  for (int qq = 0; qq < 4; ++qq) {
    float inv = 1.0f / li[qq];
    int n = n0 + 16 * w + 4 * hi + qq;
#pragma unroll
    for (int fv = 0; fv < 4; ++fv) {
      size_t idx = (size_t)(n * BZ + z) * DM + h * DH + 16 * fv + lo;
      float v = accO[fv][qq] * inv;
      unsigned short hb = f2bf(v);
      ohi[idx] = hb;
      olo[idx] = f2bf(v - bf2f(hb));
    }
  }
}

// ---------------- launch ----------------
extern "C" void kernel_launch(void* const* d_in, const int* in_sizes, int n_in,
                              void* d_out, int out_size, void* d_ws, size_t ws_size,
                              hipStream_t stream) {
  const float* x_q   = (const float*)d_in[0];
  const float* x_kv  = (const float*)d_in[1];
  const float* to_q  = (const float*)d_in[2];
  const float* to_kv = (const float*)d_in[3];
  const float* fpe   = (const float*)d_in[4];
  const float* to_o  = (const float*)d_in[5];
  float* out = (float*)d_out;

  char* W = (char*)d_ws;
  size_t o = 0;
  auto alloc = [&](size_t bytes) { char* p = W + o; o += (bytes + 255) & ~(size_t)255; return p; };
  typedef unsigned short us;
  us* q_hi  = (us*)alloc((size_t)4096 * 1024 * 2);
  us* q_lo  = (us*)alloc((size_t)4096 * 1024 * 2);
  us* kv_hi = (us*)alloc((size_t)4096 * 2048 * 2);
  us* kv_lo = (us*)alloc((size_t)4096 * 2048 * 2);
  us* tab_hi = (us*)alloc((size_t)RTAB * 1024 * 2);
  us* tab_lo = (us*)alloc((size_t)RTAB * 1024 * 2);
  us* xq_hi = (us*)alloc((size_t)4096 * 1024 * 2);  // later: sincos hi (2111*1024 fits)
  us* xq_lo = (us*)alloc((size_t)4096 * 1024 * 2);  // later: sincos lo
  us* xkv_hi = (us*)alloc((size_t)4096 * 1024 * 2); // later: attn-out hi
  us* xkv_lo = (us*)alloc((size_t)4096 * 1024 * 2); // later: attn-out lo
  us* tq_hi  = (us*)alloc((size_t)1024 * 1024 * 2);
  us* tq_lo  = (us*)alloc((size_t)1024 * 1024 * 2);
  us* tkv_hi = (us*)alloc((size_t)2048 * 1024 * 2);
  us* tkv_lo = (us*)alloc((size_t)2048 * 1024 * 2);
  us* to_hi  = (us*)alloc((size_t)1024 * 1024 * 2);
  us* to_lo  = (us*)alloc((size_t)1024 * 1024 * 2);
  us* fpe_hi = (us*)alloc((size_t)1024 * 1024 * 2);
  us* fpe_lo = (us*)alloc((size_t)1024 * 1024 * 2);

  // 1. split all fp32 inputs into (hi,lo) bf16 planes
  split_kernel<<<dim3(4096 * 1024 / 4 / 256), 256, 0, stream>>>(x_q, xq_hi, xq_lo, 4096 * 1024 / 4);
  split_kernel<<<dim3(4096 * 1024 / 4 / 256), 256, 0, stream>>>(x_kv, xkv_hi, xkv_lo, 4096 * 1024 / 4);
  split_kernel<<<dim3(1024 * 1024 / 4 / 256), 256, 0, stream>>>(to_q, tq_hi, tq_lo, 1024 * 1024 / 4);
  split_kernel<<<dim3(2048 * 1024 / 4 / 256), 256, 0, stream>>>(to_kv, tkv_hi, tkv_lo, 2048 * 1024 / 4);
  split_kernel<<<dim3(1024 * 1024 / 4 / 256), 256, 0, stream>>>(to_o, to_hi, to_lo, 1024 * 1024 / 4);
  split_kernel<<<dim3(1024 * 1024 / 4 / 256), 256, 0, stream>>>(fpe, fpe_hi, fpe_lo, 1024 * 1024 / 4);

  // 2. q = x_q @ to_q^T  -> split planes
  gemm_bf16s<1><<<dim3(8, 32), 256, 0, stream>>>(xq_hi, xq_lo, tq_hi, tq_lo,
                                                 nullptr, q_hi, q_lo, 4096, 1024, 1024);
  // 3. kv = x_kv @ to_kv^T -> split planes
  gemm_bf16s<1><<<dim3(16, 32), 256, 0, stream>>>(xkv_hi, xkv_lo, tkv_hi, tkv_lo,
                                                  nullptr, kv_hi, kv_lo, 4096, 2048, 1024);
  // 4. sincos split planes (reuse xq region, now dead)
  us* sc_hi = xq_hi;
  us* sc_lo = xq_lo;
  sincos_kernel<<<dim3((MTAB * DM + 255) / 256), 256, 0, stream>>>(sc_hi, sc_lo);
  // 5. table = sincos @ fpe^T -> split planes (rows R0TAB..)
  gemm_bf16s<1><<<dim3(8, (MTAB + 127) / 128), 256, 0, stream>>>(
      sc_hi, sc_lo, fpe_hi, fpe_lo, nullptr,
      tab_hi + (size_t)R0TAB * 1024, tab_lo + (size_t)R0TAB * 1024, MTAB, 1024, 1024);
  // 6. fused attention -> split planes (reuse xkv region, now dead)
  us* at_hi = xkv_hi;
  us* at_lo = xkv_lo;
  attn_kernel<<<dim3(NQ / 64, BZ, NH), 256, 0, stream>>>(q_hi, q_lo, kv_hi, kv_lo,
                                                         tab_hi, tab_lo, at_hi, at_lo);
  // 7. out = attn @ to_o^T -> fp32
  gemm_bf16s<0><<<dim3(8, 32), 256, 0, stream>>>(at_hi, at_lo, to_hi, to_lo,
                                                 out, nullptr, nullptr, 4096, 1024, 1024);
}

// Round 5
// 397.351 us; speedup vs baseline: 8.0571x; 1.1554x over previous
//
#include <hip/hip_runtime.h>
#include <math.h>

#define NQ 2048
#define MKV 2048
#define BZ 2
#define DM 1024
#define NH 16
#define DH 64
#define RTAB 4095  /* NQ + MKV - 1 */
#define R0TAB 1984 /* lowest table row reachable under causal mask */
#define MTAB (RTAB - R0TAB) /* 2111 */

typedef __bf16 bf16x8 __attribute__((ext_vector_type(8)));
typedef float f32x4 __attribute__((ext_vector_type(4)));

__device__ inline unsigned short f2bf(float x) {
  union { float f; unsigned u; } v; v.f = x;
  unsigned r = (v.u + 0x7FFFu + ((v.u >> 16) & 1u)) >> 16;
  return (unsigned short)r;
}
__device__ inline float bf2f(unsigned short h) {
  union { unsigned u; float f; } v; v.u = ((unsigned)h) << 16; return v.f;
}

#define SWZ(r, b) ((b) ^ (((r) & 7) << 4))

__device__ inline void gload_lds16(const void* g, void* l) {
  __builtin_amdgcn_global_load_lds((const __attribute__((address_space(1))) void*)g,
                                   (__attribute__((address_space(3))) void*)l, 16, 0, 0);
}

// ---------------- fp32 -> (hi,lo) bf16 split planes ----------------
__global__ __launch_bounds__(256) void split_kernel(const float* __restrict__ in,
                                                    unsigned short* __restrict__ hi,
                                                    unsigned short* __restrict__ lo,
                                                    int n4) {
  int i = blockIdx.x * 256 + threadIdx.x;
  if (i >= n4) return;
  float4 v = ((const float4*)in)[i];
  float f[4] = {v.x, v.y, v.z, v.w};
  ushort4 h4, l4;
  unsigned short* hp = (unsigned short*)&h4;
  unsigned short* lp = (unsigned short*)&l4;
#pragma unroll
  for (int e = 0; e < 4; ++e) {
    unsigned short hb = f2bf(f[e]);
    hp[e] = hb;
    lp[e] = f2bf(f[e] - bf2f(hb));
  }
  ((ushort4*)hi)[i] = h4;
  ((ushort4*)lo)[i] = l4;
}

// ---------------- sincos table, split planes (rows R0TAB..4094 as 0..2110) ----------------
__global__ __launch_bounds__(256) void sincos_kernel(unsigned short* __restrict__ hi,
                                                     unsigned short* __restrict__ lo) {
  int idx = blockIdx.x * 256 + threadIdx.x;
  if (idx >= MTAB * DM) return;
  int r = idx / DM;  // 0..2110 -> table row R0TAB + r
  int b = idx - r * DM;
  int i = (b < DM / 2) ? b : (b - DM / 2);
  double fr = exp((double)i * (-9.210340371976184 / 512.0));
  float rr = (float)(R0TAB + r - (MKV - 1));
  float ph = rr * (float)fr;
  float val = (b < DM / 2) ? sinf(ph) : cosf(ph);
  unsigned short hb = f2bf(val);
  hi[idx] = hb;
  lo[idx] = f2bf(val - bf2f(hb));
}

// ---------------- split-bf16 MFMA NT GEMM ----------------
template <int SPLIT_OUT>
__global__ __launch_bounds__(256, 2) void gemm_bf16s(
    const unsigned short* __restrict__ Ahi, const unsigned short* __restrict__ Alo,
    const unsigned short* __restrict__ Bhi, const unsigned short* __restrict__ Blo,
    float* __restrict__ Cf, unsigned short* __restrict__ Chi, unsigned short* __restrict__ Clo,
    int M, int N, int K) {
  __shared__ char lds[65536];
  char* sAh = lds;
  char* sAl = lds + 16384;
  char* sBh = lds + 32768;
  char* sBl = lds + 49152;
  const int t = threadIdx.x;
  const int w = t >> 6;
  const int lane = t & 63;
  const int lo = lane & 15;
  const int hi = lane >> 4;
  const int wm = w >> 1, wn = w & 1;
  const int row0 = blockIdx.y * 128;
  const int col0 = blockIdx.x * 128;

  f32x4 acc[4][4];
#pragma unroll
  for (int a = 0; a < 4; ++a)
#pragma unroll
    for (int b = 0; b < 4; ++b) acc[a][b] = (f32x4){0.f, 0.f, 0.f, 0.f};

  for (int k0 = 0; k0 < K; k0 += 64) {
#pragma unroll
    for (int i = 0; i < 4; ++i) {
      int L = i * 4096 + t * 16;
      int r = L >> 7;
      int c16 = (L >> 4) & 7;
      int g16 = c16 ^ (r & 7);
      int ra = row0 + r;
      if (ra >= M) ra = M - 1;
      int rb = col0 + r;
      const char* gah = (const char*)(Ahi + (size_t)ra * K + k0) + g16 * 16;
      const char* gal = (const char*)(Alo + (size_t)ra * K + k0) + g16 * 16;
      const char* gbh = (const char*)(Bhi + (size_t)rb * K + k0) + g16 * 16;
      const char* gbl = (const char*)(Blo + (size_t)rb * K + k0) + g16 * 16;
      gload_lds16(gah, sAh + L);
      gload_lds16(gal, sAl + L);
      gload_lds16(gbh, sBh + L);
      gload_lds16(gbl, sBl + L);
    }
    __syncthreads();
#pragma unroll
    for (int ks = 0; ks < 2; ++ks) {
      bf16x8 ah[4], al[4], bh[4], bl[4];
#pragma unroll
      for (int f = 0; f < 4; ++f) {
        int rA = wm * 64 + 16 * f + lo;
        int offA = rA * 128 + (((4 * ks + hi) ^ (rA & 7)) << 4);
        ah[f] = *(const bf16x8*)(sAh + offA);
        al[f] = *(const bf16x8*)(sAl + offA);
        int rB = wn * 64 + 16 * f + lo;
        int offB = rB * 128 + (((4 * ks + hi) ^ (rB & 7)) << 4);
        bh[f] = *(const bf16x8*)(sBh + offB);
        bl[f] = *(const bf16x8*)(sBl + offB);
      }
#pragma unroll
      for (int fm = 0; fm < 4; ++fm)
#pragma unroll
        for (int fn = 0; fn < 4; ++fn) {
          acc[fm][fn] = __builtin_amdgcn_mfma_f32_16x16x32_bf16(ah[fm], bh[fn], acc[fm][fn], 0, 0, 0);
          acc[fm][fn] = __builtin_amdgcn_mfma_f32_16x16x32_bf16(ah[fm], bl[fn], acc[fm][fn], 0, 0, 0);
          acc[fm][fn] = __builtin_amdgcn_mfma_f32_16x16x32_bf16(al[fm], bh[fn], acc[fm][fn], 0, 0, 0);
        }
    }
    __syncthreads();
  }
  // epilogue
#pragma unroll
  for (int fm = 0; fm < 4; ++fm)
#pragma unroll
    for (int qq = 0; qq < 4; ++qq) {
      int row = row0 + wm * 64 + 16 * fm + 4 * hi + qq;
      if (row < M) {
#pragma unroll
        for (int fn = 0; fn < 4; ++fn) {
          int col = col0 + wn * 64 + 16 * fn + lo;
          float v = acc[fm][fn][qq];
          if (SPLIT_OUT) {
            unsigned short hb = f2bf(v);
            Chi[(size_t)row * N + col] = hb;
            Clo[(size_t)row * N + col] = f2bf(v - bf2f(hb));
          } else {
            Cf[(size_t)row * N + col] = v;
          }
        }
      }
    }
}

// ---------------- MFMA fused causal attention, split-bf16 inputs ----------------
// Persistent balanced schedule: 512 blocks, block i does items {1023-i, i}
// (item = qb*32 + z*16 + h) -> exactly 33 kv-tiles per block.
// T14 async staging: next tile's K/T/V issued into regs during current tile's compute.
union U8 { uint4 q; unsigned short u[8]; };

__global__ __launch_bounds__(256, 2) void attn_kernel(
    const unsigned short* __restrict__ qhi, const unsigned short* __restrict__ qlo,
    const unsigned short* __restrict__ kvhi, const unsigned short* __restrict__ kvlo,
    const unsigned short* __restrict__ tabhi, const unsigned short* __restrict__ tablo,
    unsigned short* __restrict__ ohi, unsigned short* __restrict__ olo) {
  __shared__ __align__(16) char sKhi[8192];   // K hi bf16 [64][64], swizzled
  __shared__ __align__(16) char sKlo[8192];   // K lo
  __shared__ __align__(16) char sT[32768];    // Thi/Tlo; later per-wave PL f32 bounce
  __shared__ __align__(16) char sVT[8192];    // V^T bf16 [64 dv][64 m], swizzled
  __shared__ __align__(16) char sP[8192];     // P bf16 [64 n][64 m], swizzled

  const int t = threadIdx.x;
  const int w = t >> 6;
  const int lane = t & 63;
  const int lo = lane & 15;
  const int hi = lane >> 4;

  for (int rep = 0; rep < 2; ++rep) {
    const int item = rep == 0 ? (1023 - (int)blockIdx.x) : (int)blockIdx.x;
    const int qb = item >> 5;
    const int z = (item >> 4) & 1;
    const int h = item & 15;
    const int n0 = qb * 64;

    // ---- Q fragments straight from split planes
    bf16x8 qh[2], ql[2];
    {
      size_t qoff = (size_t)((n0 + 16 * w + lo) * BZ + z) * DM + h * DH;
#pragma unroll
      for (int ks = 0; ks < 2; ++ks) {
        qh[ks] = *(const bf16x8*)(qhi + qoff + 32 * ks + 8 * hi);
        ql[ks] = *(const bf16x8*)(qlo + qoff + 32 * ks + 8 * hi);
      }
    }

    f32x4 accO[4];
#pragma unroll
    for (int f = 0; f < 4; ++f) accO[f] = (f32x4){0.f, 0.f, 0.f, 0.f};
    float mi[4], li[4];
#pragma unroll
    for (int qq = 0; qq < 4; ++qq) { mi[qq] = -1e30f; li[qq] = 0.f; }

    // prefetch registers
    uint4 pKh[2], pKl[2], pVh[2], pTh[4], pTl[4];

    // issue tile-0 loads
    {
      const int m0 = 0;
      const int Wb = n0 - m0 + R0TAB;
#pragma unroll
      for (int it = 0; it < 2; ++it) {
        int f = it * 256 + t;
        int j = f >> 3;
        int d8 = (f & 7) << 3;
        size_t gb = (size_t)((m0 + j) * BZ + z) * (NH * 2 * DH) + h * (2 * DH);
        pKh[it] = *(const uint4*)(kvhi + gb + d8);
        pKl[it] = *(const uint4*)(kvlo + gb + d8);
        pVh[it] = *(const uint4*)(kvhi + gb + DH + d8);
      }
#pragma unroll
      for (int it = 0; it < 4; ++it) {
        int f = it * 256 + t;
        int rr = f >> 3;
        int rc = rr < 127 ? rr : 126;
        int d8 = (f & 7) << 3;
        size_t gb = (size_t)(Wb + rc) * DM + h * DH + d8;
        pTh[it] = *(const uint4*)(tabhi + gb);
        pTl[it] = *(const uint4*)(tablo + gb);
      }
    }

    for (int mt = 0; mt <= qb; ++mt) {
      __syncthreads();  // prior tile's (or item's) LDS reads complete

      // ---- write prefetched K/V/T regs -> LDS
#pragma unroll
      for (int it = 0; it < 2; ++it) {
        int f = it * 256 + t;
        int j = f >> 3;
        int d8 = (f & 7) << 3;
        int kb = SWZ(j, j * 128 + d8 * 2);
        *(uint4*)(sKhi + kb) = pKh[it];
        *(uint4*)(sKlo + kb) = pKl[it];
        U8 vh;
        vh.q = pVh[it];
#pragma unroll
        for (int e = 0; e < 8; ++e) {
          int dv = d8 + e;
          *(unsigned short*)(sVT + SWZ(dv, dv * 128 + j * 2)) = vh.u[e];
        }
      }
#pragma unroll
      for (int it = 0; it < 4; ++it) {
        int f = it * 256 + t;
        int rr = f >> 3;
        int d8 = (f & 7) << 3;
        int tb = SWZ(rr, rr * 128 + d8 * 2);
        *(uint4*)(sT + tb) = pTh[it];
        *(uint4*)(sT + 16384 + tb) = pTl[it];
      }

      // ---- issue next tile's loads (hidden under this tile's compute)
      if (mt < qb) {
        const int m0n = (mt + 1) * 64;
        const int Wbn = n0 - m0n + R0TAB;
#pragma unroll
        for (int it = 0; it < 2; ++it) {
          int f = it * 256 + t;
          int j = f >> 3;
          int d8 = (f & 7) << 3;
          size_t gb = (size_t)((m0n + j) * BZ + z) * (NH * 2 * DH) + h * (2 * DH);
          pKh[it] = *(const uint4*)(kvhi + gb + d8);
          pKl[it] = *(const uint4*)(kvlo + gb + d8);
          pVh[it] = *(const uint4*)(kvhi + gb + DH + d8);
        }
#pragma unroll
        for (int it = 0; it < 4; ++it) {
          int f = it * 256 + t;
          int rr = f >> 3;
          int rc = rr < 127 ? rr : 126;
          int d8 = (f & 7) << 3;
          size_t gb = (size_t)(Wbn + rc) * DM + h * DH + d8;
          pTh[it] = *(const uint4*)(tabhi + gb);
          pTl[it] = *(const uint4*)(tablo + gb);
        }
      }
      __syncthreads();

      // ---- S = QK^T and PL = QT^T, split-bf16 MFMA
      f32x4 accS[4], accPL[5];
#pragma unroll
      for (int f = 0; f < 4; ++f) accS[f] = (f32x4){0.f, 0.f, 0.f, 0.f};
#pragma unroll
      for (int f = 0; f < 5; ++f) accPL[f] = (f32x4){0.f, 0.f, 0.f, 0.f};
#pragma unroll
      for (int ks = 0; ks < 2; ++ks) {
#pragma unroll
        for (int fm = 0; fm < 4; ++fm) {
          int rb = SWZ(lo, (16 * fm + lo) * 128 + (32 * ks + 8 * hi) * 2);
          bf16x8 kh = *(const bf16x8*)(sKhi + rb);
          bf16x8 kl = *(const bf16x8*)(sKlo + rb);
          accS[fm] = __builtin_amdgcn_mfma_f32_16x16x32_bf16(qh[ks], kh, accS[fm], 0, 0, 0);
          accS[fm] = __builtin_amdgcn_mfma_f32_16x16x32_bf16(qh[ks], kl, accS[fm], 0, 0, 0);
          accS[fm] = __builtin_amdgcn_mfma_f32_16x16x32_bf16(ql[ks], kh, accS[fm], 0, 0, 0);
        }
#pragma unroll
        for (int fr = 0; fr < 5; ++fr) {
          int r = 16 * (w + fr) + lo;
          int rb = SWZ(lo, r * 128 + (32 * ks + 8 * hi) * 2);
          bf16x8 th = *(const bf16x8*)(sT + rb);
          bf16x8 tl = *(const bf16x8*)(sT + 16384 + rb);
          accPL[fr] = __builtin_amdgcn_mfma_f32_16x16x32_bf16(qh[ks], th, accPL[fr], 0, 0, 0);
          accPL[fr] = __builtin_amdgcn_mfma_f32_16x16x32_bf16(qh[ks], tl, accPL[fr], 0, 0, 0);
          accPL[fr] = __builtin_amdgcn_mfma_f32_16x16x32_bf16(ql[ks], th, accPL[fr], 0, 0, 0);
        }
      }
      __syncthreads();  // all T reads done before PL overwrites sT

      // ---- PL bounce to per-wave LDS region (aliases sT), then diagonal gather
      float* plb = (float*)sT + (size_t)w * 16 * 84;
#pragma unroll
      for (int fr = 0; fr < 5; ++fr)
#pragma unroll
        for (int qq = 0; qq < 4; ++qq)
          plb[(4 * hi + qq) * 84 + 16 * fr + lo] = accPL[fr][qq];
#pragma unroll
      for (int fm = 0; fm < 4; ++fm)
#pragma unroll
        for (int qq = 0; qq < 4; ++qq) {
          int rn = 4 * hi + qq + 63 - 16 * fm - lo;  // in [0,78]
          accS[fm][qq] += plb[(4 * hi + qq) * 84 + rn];
        }

      if (mt == qb) {  // diagonal tile: mask m > n
#pragma unroll
        for (int fm = 0; fm < 4; ++fm)
#pragma unroll
          for (int qq = 0; qq < 4; ++qq)
            if (16 * fm + lo > 16 * w + 4 * hi + qq) accS[fm][qq] = -1e30f;
      }

      // ---- online softmax in registers
#pragma unroll
      for (int qq = 0; qq < 4; ++qq) {
        float pm = fmaxf(fmaxf(accS[0][qq], accS[1][qq]), fmaxf(accS[2][qq], accS[3][qq]));
        pm = fmaxf(pm, __shfl_xor(pm, 1));
        pm = fmaxf(pm, __shfl_xor(pm, 2));
        pm = fmaxf(pm, __shfl_xor(pm, 4));
        pm = fmaxf(pm, __shfl_xor(pm, 8));
        float mn = fmaxf(mi[qq], pm);
        float a = __expf(mi[qq] - mn);
        mi[qq] = mn;
        float rs = 0.f;
#pragma unroll
        for (int fm = 0; fm < 4; ++fm) {
          float p = __expf(accS[fm][qq] - mn);
          accS[fm][qq] = p;
          rs += p;
        }
        rs += __shfl_xor(rs, 1);
        rs += __shfl_xor(rs, 2);
        rs += __shfl_xor(rs, 4);
        rs += __shfl_xor(rs, 8);
        li[qq] = li[qq] * a + rs;
#pragma unroll
        for (int f = 0; f < 4; ++f) accO[f][qq] *= a;
      }

      // ---- P -> LDS bf16 (wave-local rows)
#pragma unroll
      for (int fm = 0; fm < 4; ++fm)
#pragma unroll
        for (int qq = 0; qq < 4; ++qq) {
          int row = 16 * w + 4 * hi + qq;
          *(unsigned short*)(sP + SWZ(4 * hi + qq, row * 128 + (16 * fm + lo) * 2)) =
              f2bf(accS[fm][qq]);
        }

      // ---- PV: accO += P @ V
#pragma unroll
      for (int ks = 0; ks < 2; ++ks) {
        int ab = SWZ(lo, (16 * w + lo) * 128 + (32 * ks + 8 * hi) * 2);
        bf16x8 pa = *(const bf16x8*)(sP + ab);
#pragma unroll
        for (int fv = 0; fv < 4; ++fv) {
          int vb = SWZ(lo, (16 * fv + lo) * 128 + (32 * ks + 8 * hi) * 2);
          bf16x8 vv = *(const bf16x8*)(sVT + vb);
          accO[fv] = __builtin_amdgcn_mfma_f32_16x16x32_bf16(pa, vv, accO[fv], 0, 0, 0);
        }
      }
    }

    // ---- epilogue: attn = accO / li, written as split planes
#pragma unroll
    for (int qq = 0; qq < 4; ++qq) {
      float inv = 1.0f / li[qq];
      int n = n0 + 16 * w + 4 * hi + qq;
#pragma unroll
      for (int fv = 0; fv < 4; ++fv) {
        size_t idx = (size_t)(n * BZ + z) * DM + h * DH + 16 * fv + lo;
        float v = accO[fv][qq] * inv;
        unsigned short hb = f2bf(v);
        ohi[idx] = hb;
        olo[idx] = f2bf(v - bf2f(hb));
      }
    }
  }
}

// ---------------- launch ----------------
extern "C" void kernel_launch(void* const* d_in, const int* in_sizes, int n_in,
                              void* d_out, int out_size, void* d_ws, size_t ws_size,
                              hipStream_t stream) {
  const float* x_q   = (const float*)d_in[0];
  const float* x_kv  = (const float*)d_in[1];
  const float* to_q  = (const float*)d_in[2];
  const float* to_kv = (const float*)d_in[3];
  const float* fpe   = (const float*)d_in[4];
  const float* to_o  = (const float*)d_in[5];
  float* out = (float*)d_out;

  char* W = (char*)d_ws;
  size_t o = 0;
  auto alloc = [&](size_t bytes) { char* p = W + o; o += (bytes + 255) & ~(size_t)255; return p; };
  typedef unsigned short us;
  us* q_hi  = (us*)alloc((size_t)4096 * 1024 * 2);
  us* q_lo  = (us*)alloc((size_t)4096 * 1024 * 2);
  us* kv_hi = (us*)alloc((size_t)4096 * 2048 * 2);
  us* kv_lo = (us*)alloc((size_t)4096 * 2048 * 2);
  us* tab_hi = (us*)alloc((size_t)RTAB * 1024 * 2);
  us* tab_lo = (us*)alloc((size_t)RTAB * 1024 * 2);
  us* xq_hi = (us*)alloc((size_t)4096 * 1024 * 2);  // later: sincos hi
  us* xq_lo = (us*)alloc((size_t)4096 * 1024 * 2);  // later: sincos lo
  us* xkv_hi = (us*)alloc((size_t)4096 * 1024 * 2); // later: attn-out hi
  us* xkv_lo = (us*)alloc((size_t)4096 * 1024 * 2); // later: attn-out lo
  us* tq_hi  = (us*)alloc((size_t)1024 * 1024 * 2);
  us* tq_lo  = (us*)alloc((size_t)1024 * 1024 * 2);
  us* tkv_hi = (us*)alloc((size_t)2048 * 1024 * 2);
  us* tkv_lo = (us*)alloc((size_t)2048 * 1024 * 2);
  us* to_hi  = (us*)alloc((size_t)1024 * 1024 * 2);
  us* to_lo  = (us*)alloc((size_t)1024 * 1024 * 2);
  us* fpe_hi = (us*)alloc((size_t)1024 * 1024 * 2);
  us* fpe_lo = (us*)alloc((size_t)1024 * 1024 * 2);

  // 1. split all fp32 inputs into (hi,lo) bf16 planes
  split_kernel<<<dim3(4096 * 1024 / 4 / 256), 256, 0, stream>>>(x_q, xq_hi, xq_lo, 4096 * 1024 / 4);
  split_kernel<<<dim3(4096 * 1024 / 4 / 256), 256, 0, stream>>>(x_kv, xkv_hi, xkv_lo, 4096 * 1024 / 4);
  split_kernel<<<dim3(1024 * 1024 / 4 / 256), 256, 0, stream>>>(to_q, tq_hi, tq_lo, 1024 * 1024 / 4);
  split_kernel<<<dim3(2048 * 1024 / 4 / 256), 256, 0, stream>>>(to_kv, tkv_hi, tkv_lo, 2048 * 1024 / 4);
  split_kernel<<<dim3(1024 * 1024 / 4 / 256), 256, 0, stream>>>(to_o, to_hi, to_lo, 1024 * 1024 / 4);
  split_kernel<<<dim3(1024 * 1024 / 4 / 256), 256, 0, stream>>>(fpe, fpe_hi, fpe_lo, 1024 * 1024 / 4);

  // 2. q = x_q @ to_q^T  -> split planes
  gemm_bf16s<1><<<dim3(8, 32), 256, 0, stream>>>(xq_hi, xq_lo, tq_hi, tq_lo,
                                                 nullptr, q_hi, q_lo, 4096, 1024, 1024);
  // 3. kv = x_kv @ to_kv^T -> split planes
  gemm_bf16s<1><<<dim3(16, 32), 256, 0, stream>>>(xkv_hi, xkv_lo, tkv_hi, tkv_lo,
                                                  nullptr, kv_hi, kv_lo, 4096, 2048, 1024);
  // 4. sincos split planes (reuse xq region, now dead)
  us* sc_hi = xq_hi;
  us* sc_lo = xq_lo;
  sincos_kernel<<<dim3((MTAB * DM + 255) / 256), 256, 0, stream>>>(sc_hi, sc_lo);
  // 5. table = sincos @ fpe^T -> split planes (rows R0TAB..)
  gemm_bf16s<1><<<dim3(8, (MTAB + 127) / 128), 256, 0, stream>>>(
      sc_hi, sc_lo, fpe_hi, fpe_lo, nullptr,
      tab_hi + (size_t)R0TAB * 1024, tab_lo + (size_t)R0TAB * 1024, MTAB, 1024, 1024);
  // 6. fused attention (balanced persistent grid) -> split planes (reuse xkv region)
  us* at_hi = xkv_hi;
  us* at_lo = xkv_lo;
  attn_kernel<<<dim3(512), 256, 0, stream>>>(q_hi, q_lo, kv_hi, kv_lo,
                                             tab_hi, tab_lo, at_hi, at_lo);
  // 7. out = attn @ to_o^T -> fp32
  gemm_bf16s<0><<<dim3(8, 32), 256, 0, stream>>>(at_hi, at_lo, to_hi, to_lo,
                                                 out, nullptr, nullptr, 4096, 1024, 1024);
}

// Round 6
// 333.453 us; speedup vs baseline: 9.6011x; 1.1916x over previous
//
#include <hip/hip_runtime.h>
#include <math.h>

#define NQ 2048
#define MKV 2048
#define BZ 2
#define DM 1024
#define NH 16
#define DH 64
#define RTAB 4095  /* NQ + MKV - 1 */
#define R0TAB 1984 /* lowest table row reachable under causal mask */
#define MTAB (RTAB - R0TAB) /* 2111 */

typedef __bf16 bf16x8 __attribute__((ext_vector_type(8)));
typedef float f32x4 __attribute__((ext_vector_type(4)));

__device__ inline unsigned short f2bf(float x) {
  union { float f; unsigned u; } v; v.f = x;
  unsigned r = (v.u + 0x7FFFu + ((v.u >> 16) & 1u)) >> 16;
  return (unsigned short)r;
}
__device__ inline float bf2f(unsigned short h) {
  union { unsigned u; float f; } v; v.u = ((unsigned)h) << 16; return v.f;
}

#define SWZ(r, b) ((b) ^ (((r) & 7) << 4))

__device__ inline void gload_lds16(const void* g, void* l) {
  __builtin_amdgcn_global_load_lds((const __attribute__((address_space(1))) void*)g,
                                   (__attribute__((address_space(3))) void*)l, 16, 0, 0);
}

// ---------------- fp32 -> (hi,lo) bf16 split planes ----------------
__global__ __launch_bounds__(256) void split_kernel(const float* __restrict__ in,
                                                    unsigned short* __restrict__ hi,
                                                    unsigned short* __restrict__ lo,
                                                    int n4) {
  int i = blockIdx.x * 256 + threadIdx.x;
  if (i >= n4) return;
  float4 v = ((const float4*)in)[i];
  float f[4] = {v.x, v.y, v.z, v.w};
  ushort4 h4, l4;
  unsigned short* hp = (unsigned short*)&h4;
  unsigned short* lp = (unsigned short*)&l4;
#pragma unroll
  for (int e = 0; e < 4; ++e) {
    unsigned short hb = f2bf(f[e]);
    hp[e] = hb;
    lp[e] = f2bf(f[e] - bf2f(hb));
  }
  ((ushort4*)hi)[i] = h4;
  ((ushort4*)lo)[i] = l4;
}

// ---------------- sincos table, split planes (rows R0TAB..4094 as 0..2110) ----------------
__global__ __launch_bounds__(256) void sincos_kernel(unsigned short* __restrict__ hi,
                                                     unsigned short* __restrict__ lo) {
  int idx = blockIdx.x * 256 + threadIdx.x;
  if (idx >= MTAB * DM) return;
  int r = idx / DM;  // 0..2110 -> table row R0TAB + r
  int b = idx - r * DM;
  int i = (b < DM / 2) ? b : (b - DM / 2);
  double fr = exp((double)i * (-9.210340371976184 / 512.0));
  float rr = (float)(R0TAB + r - (MKV - 1));
  float ph = rr * (float)fr;
  float val = (b < DM / 2) ? sinf(ph) : cosf(ph);
  unsigned short hb = f2bf(val);
  hi[idx] = hb;
  lo[idx] = f2bf(val - bf2f(hb));
}

// ---------------- split-bf16 MFMA NT GEMM ----------------
template <int SPLIT_OUT>
__global__ __launch_bounds__(256, 2) void gemm_bf16s(
    const unsigned short* __restrict__ Ahi, const unsigned short* __restrict__ Alo,
    const unsigned short* __restrict__ Bhi, const unsigned short* __restrict__ Blo,
    float* __restrict__ Cf, unsigned short* __restrict__ Chi, unsigned short* __restrict__ Clo,
    int M, int N, int K) {
  __shared__ char lds[65536];
  char* sAh = lds;
  char* sAl = lds + 16384;
  char* sBh = lds + 32768;
  char* sBl = lds + 49152;
  const int t = threadIdx.x;
  const int w = t >> 6;
  const int lane = t & 63;
  const int lo = lane & 15;
  const int hi = lane >> 4;
  const int wm = w >> 1, wn = w & 1;
  const int row0 = blockIdx.y * 128;
  const int col0 = blockIdx.x * 128;

  f32x4 acc[4][4];
#pragma unroll
  for (int a = 0; a < 4; ++a)
#pragma unroll
    for (int b = 0; b < 4; ++b) acc[a][b] = (f32x4){0.f, 0.f, 0.f, 0.f};

  for (int k0 = 0; k0 < K; k0 += 64) {
#pragma unroll
    for (int i = 0; i < 4; ++i) {
      int L = i * 4096 + t * 16;
      int r = L >> 7;
      int c16 = (L >> 4) & 7;
      int g16 = c16 ^ (r & 7);
      int ra = row0 + r;
      if (ra >= M) ra = M - 1;
      int rb = col0 + r;
      const char* gah = (const char*)(Ahi + (size_t)ra * K + k0) + g16 * 16;
      const char* gal = (const char*)(Alo + (size_t)ra * K + k0) + g16 * 16;
      const char* gbh = (const char*)(Bhi + (size_t)rb * K + k0) + g16 * 16;
      const char* gbl = (const char*)(Blo + (size_t)rb * K + k0) + g16 * 16;
      gload_lds16(gah, sAh + L);
      gload_lds16(gal, sAl + L);
      gload_lds16(gbh, sBh + L);
      gload_lds16(gbl, sBl + L);
    }
    __syncthreads();
#pragma unroll
    for (int ks = 0; ks < 2; ++ks) {
      bf16x8 ah[4], al[4], bh[4], bl[4];
#pragma unroll
      for (int f = 0; f < 4; ++f) {
        int rA = wm * 64 + 16 * f + lo;
        int offA = rA * 128 + (((4 * ks + hi) ^ (rA & 7)) << 4);
        ah[f] = *(const bf16x8*)(sAh + offA);
        al[f] = *(const bf16x8*)(sAl + offA);
        int rB = wn * 64 + 16 * f + lo;
        int offB = rB * 128 + (((4 * ks + hi) ^ (rB & 7)) << 4);
        bh[f] = *(const bf16x8*)(sBh + offB);
        bl[f] = *(const bf16x8*)(sBl + offB);
      }
#pragma unroll
      for (int fm = 0; fm < 4; ++fm)
#pragma unroll
        for (int fn = 0; fn < 4; ++fn) {
          acc[fm][fn] = __builtin_amdgcn_mfma_f32_16x16x32_bf16(ah[fm], bh[fn], acc[fm][fn], 0, 0, 0);
          acc[fm][fn] = __builtin_amdgcn_mfma_f32_16x16x32_bf16(ah[fm], bl[fn], acc[fm][fn], 0, 0, 0);
          acc[fm][fn] = __builtin_amdgcn_mfma_f32_16x16x32_bf16(al[fm], bh[fn], acc[fm][fn], 0, 0, 0);
        }
    }
    __syncthreads();
  }
  // epilogue
#pragma unroll
  for (int fm = 0; fm < 4; ++fm)
#pragma unroll
    for (int qq = 0; qq < 4; ++qq) {
      int row = row0 + wm * 64 + 16 * fm + 4 * hi + qq;
      if (row < M) {
#pragma unroll
        for (int fn = 0; fn < 4; ++fn) {
          int col = col0 + wn * 64 + 16 * fn + lo;
          float v = acc[fm][fn][qq];
          if (SPLIT_OUT) {
            unsigned short hb = f2bf(v);
            Chi[(size_t)row * N + col] = hb;
            Clo[(size_t)row * N + col] = f2bf(v - bf2f(hb));
          } else {
            Cf[(size_t)row * N + col] = v;
          }
        }
      }
    }
}

// ---------------- MFMA fused causal attention, split-bf16 inputs ----------------
// Persistent balanced schedule: 512 blocks, block i does items {1023-i, i}
// (item = qb*32 + z*16 + h) -> exactly 33 kv-tiles per block.
// K/T staged via async global_load_lds with pre-swizzled source (zero VGPR cost);
// only V is register-staged (2 uint4) for the transpose write.
union U8 { uint4 q; unsigned short u[8]; };

__global__ __launch_bounds__(256, 2) void attn_kernel(
    const unsigned short* __restrict__ qhi, const unsigned short* __restrict__ qlo,
    const unsigned short* __restrict__ kvhi, const unsigned short* __restrict__ kvlo,
    const unsigned short* __restrict__ tabhi, const unsigned short* __restrict__ tablo,
    unsigned short* __restrict__ ohi, unsigned short* __restrict__ olo) {
  __shared__ __align__(16) char sKhi[8192];   // K hi bf16 [64][64], swizzled
  __shared__ __align__(16) char sKlo[8192];   // K lo
  __shared__ __align__(16) char sT[32768];    // Thi/Tlo; later per-wave PL f32 bounce
  __shared__ __align__(16) char sVT[8192];    // V^T bf16 [64 dv][64 m], swizzled
  __shared__ __align__(16) char sP[8192];     // P bf16 [64 n][64 m], swizzled

  const int t = threadIdx.x;
  const int w = t >> 6;
  const int lane = t & 63;
  const int lo = lane & 15;
  const int hi = lane >> 4;

  for (int rep = 0; rep < 2; ++rep) {
    const int item = rep == 0 ? (1023 - (int)blockIdx.x) : (int)blockIdx.x;
    const int qb = item >> 5;
    const int z = (item >> 4) & 1;
    const int h = item & 15;
    const int n0 = qb * 64;

    // ---- Q fragments straight from split planes
    bf16x8 qh[2], ql[2];
    {
      size_t qoff = (size_t)((n0 + 16 * w + lo) * BZ + z) * DM + h * DH;
#pragma unroll
      for (int ks = 0; ks < 2; ++ks) {
        qh[ks] = *(const bf16x8*)(qhi + qoff + 32 * ks + 8 * hi);
        ql[ks] = *(const bf16x8*)(qlo + qoff + 32 * ks + 8 * hi);
      }
    }

    f32x4 accO[4];
#pragma unroll
    for (int f = 0; f < 4; ++f) accO[f] = (f32x4){0.f, 0.f, 0.f, 0.f};
    float mi[4], li[4];
#pragma unroll
    for (int qq = 0; qq < 4; ++qq) { mi[qq] = -1e30f; li[qq] = 0.f; }

    // V register staging (2 uint4 only)
    uint4 pVh[2];
#pragma unroll
    for (int it = 0; it < 2; ++it) {
      int f = it * 256 + t;
      int j = f >> 3;
      int d8 = (f & 7) << 3;
      size_t gb = (size_t)((0 + j) * BZ + z) * (NH * 2 * DH) + h * (2 * DH);
      pVh[it] = *(const uint4*)(kvhi + gb + DH + d8);
    }

    for (int mt = 0; mt <= qb; ++mt) {
      const int m0 = mt * 64;
      const int Wb = n0 - m0 + R0TAB;
      __syncthreads();  // prior tile's LDS reads complete before restaging

      // ---- async stage K hi/lo (pre-swizzled source -> linear LDS dest)
#pragma unroll
      for (int it = 0; it < 2; ++it) {
        int f = it * 256 + t;
        int j = f >> 3;        // 0..63
        int c = f & 7;         // 16B chunk
        int gsw = (c ^ (j & 7)) << 3;  // element offset of swizzled chunk
        size_t gb = (size_t)((m0 + j) * BZ + z) * (NH * 2 * DH) + h * (2 * DH);
        gload_lds16(kvhi + gb + gsw, sKhi + f * 16);
        gload_lds16(kvlo + gb + gsw, sKlo + f * 16);
      }
      // ---- async stage T window hi/lo (128 rows; row 127 clamped, never read)
#pragma unroll
      for (int it = 0; it < 4; ++it) {
        int f = it * 256 + t;
        int rr = f >> 3;       // 0..127
        int rc = rr < 127 ? rr : 126;
        int c = f & 7;
        int gsw = (c ^ (rr & 7)) << 3;
        size_t gb = (size_t)(Wb + rc) * DM + h * DH;
        gload_lds16(tabhi + gb + gsw, sT + f * 16);
        gload_lds16(tablo + gb + gsw, sT + 16384 + f * 16);
      }

      // ---- write this tile's V^T from regs
#pragma unroll
      for (int it = 0; it < 2; ++it) {
        int f = it * 256 + t;
        int j = f >> 3;
        int d8 = (f & 7) << 3;
        U8 vh;
        vh.q = pVh[it];
#pragma unroll
        for (int e = 0; e < 8; ++e) {
          int dv = d8 + e;
          *(unsigned short*)(sVT + SWZ(dv, dv * 128 + j * 2)) = vh.u[e];
        }
      }
      // ---- issue next tile's V loads (land during this tile's compute)
      if (mt < qb) {
        const int m0n = (mt + 1) * 64;
#pragma unroll
        for (int it = 0; it < 2; ++it) {
          int f = it * 256 + t;
          int j = f >> 3;
          int d8 = (f & 7) << 3;
          size_t gb = (size_t)((m0n + j) * BZ + z) * (NH * 2 * DH) + h * (2 * DH);
          pVh[it] = *(const uint4*)(kvhi + gb + DH + d8);
        }
      }
      __syncthreads();  // drains gload_lds (vmcnt) + V^T ds writes

      // ---- S = QK^T and PL = QT^T, split-bf16 MFMA
      f32x4 accS[4], accPL[5];
#pragma unroll
      for (int f = 0; f < 4; ++f) accS[f] = (f32x4){0.f, 0.f, 0.f, 0.f};
#pragma unroll
      for (int f = 0; f < 5; ++f) accPL[f] = (f32x4){0.f, 0.f, 0.f, 0.f};
#pragma unroll
      for (int ks = 0; ks < 2; ++ks) {
#pragma unroll
        for (int fm = 0; fm < 4; ++fm) {
          int rb = SWZ(lo, (16 * fm + lo) * 128 + (32 * ks + 8 * hi) * 2);
          bf16x8 kh = *(const bf16x8*)(sKhi + rb);
          bf16x8 kl = *(const bf16x8*)(sKlo + rb);
          accS[fm] = __builtin_amdgcn_mfma_f32_16x16x32_bf16(qh[ks], kh, accS[fm], 0, 0, 0);
          accS[fm] = __builtin_amdgcn_mfma_f32_16x16x32_bf16(qh[ks], kl, accS[fm], 0, 0, 0);
          accS[fm] = __builtin_amdgcn_mfma_f32_16x16x32_bf16(ql[ks], kh, accS[fm], 0, 0, 0);
        }
#pragma unroll
        for (int fr = 0; fr < 5; ++fr) {
          int r = 16 * (w + fr) + lo;
          int rb = SWZ(lo, r * 128 + (32 * ks + 8 * hi) * 2);
          bf16x8 th = *(const bf16x8*)(sT + rb);
          bf16x8 tl = *(const bf16x8*)(sT + 16384 + rb);
          accPL[fr] = __builtin_amdgcn_mfma_f32_16x16x32_bf16(qh[ks], th, accPL[fr], 0, 0, 0);
          accPL[fr] = __builtin_amdgcn_mfma_f32_16x16x32_bf16(qh[ks], tl, accPL[fr], 0, 0, 0);
          accPL[fr] = __builtin_amdgcn_mfma_f32_16x16x32_bf16(ql[ks], th, accPL[fr], 0, 0, 0);
        }
      }
      __syncthreads();  // all T reads done before PL overwrites sT

      // ---- PL bounce to per-wave LDS region (aliases sT), then diagonal gather
      float* plb = (float*)sT + (size_t)w * 16 * 84;
#pragma unroll
      for (int fr = 0; fr < 5; ++fr)
#pragma unroll
        for (int qq = 0; qq < 4; ++qq)
          plb[(4 * hi + qq) * 84 + 16 * fr + lo] = accPL[fr][qq];
#pragma unroll
      for (int fm = 0; fm < 4; ++fm)
#pragma unroll
        for (int qq = 0; qq < 4; ++qq) {
          int rn = 4 * hi + qq + 63 - 16 * fm - lo;  // in [0,78]
          accS[fm][qq] += plb[(4 * hi + qq) * 84 + rn];
        }

      if (mt == qb) {  // diagonal tile: mask m > n
#pragma unroll
        for (int fm = 0; fm < 4; ++fm)
#pragma unroll
          for (int qq = 0; qq < 4; ++qq)
            if (16 * fm + lo > 16 * w + 4 * hi + qq) accS[fm][qq] = -1e30f;
      }

      // ---- online softmax in registers
#pragma unroll
      for (int qq = 0; qq < 4; ++qq) {
        float pm = fmaxf(fmaxf(accS[0][qq], accS[1][qq]), fmaxf(accS[2][qq], accS[3][qq]));
        pm = fmaxf(pm, __shfl_xor(pm, 1));
        pm = fmaxf(pm, __shfl_xor(pm, 2));
        pm = fmaxf(pm, __shfl_xor(pm, 4));
        pm = fmaxf(pm, __shfl_xor(pm, 8));
        float mn = fmaxf(mi[qq], pm);
        float a = __expf(mi[qq] - mn);
        mi[qq] = mn;
        float rs = 0.f;
#pragma unroll
        for (int fm = 0; fm < 4; ++fm) {
          float p = __expf(accS[fm][qq] - mn);
          accS[fm][qq] = p;
          rs += p;
        }
        rs += __shfl_xor(rs, 1);
        rs += __shfl_xor(rs, 2);
        rs += __shfl_xor(rs, 4);
        rs += __shfl_xor(rs, 8);
        li[qq] = li[qq] * a + rs;
#pragma unroll
        for (int f = 0; f < 4; ++f) accO[f][qq] *= a;
      }

      // ---- P -> LDS bf16 (wave-local rows)
#pragma unroll
      for (int fm = 0; fm < 4; ++fm)
#pragma unroll
        for (int qq = 0; qq < 4; ++qq) {
          int row = 16 * w + 4 * hi + qq;
          *(unsigned short*)(sP + SWZ(4 * hi + qq, row * 128 + (16 * fm + lo) * 2)) =
              f2bf(accS[fm][qq]);
        }

      // ---- PV: accO += P @ V
#pragma unroll
      for (int ks = 0; ks < 2; ++ks) {
        int ab = SWZ(lo, (16 * w + lo) * 128 + (32 * ks + 8 * hi) * 2);
        bf16x8 pa = *(const bf16x8*)(sP + ab);
#pragma unroll
        for (int fv = 0; fv < 4; ++fv) {
          int vb = SWZ(lo, (16 * fv + lo) * 128 + (32 * ks + 8 * hi) * 2);
          bf16x8 vv = *(const bf16x8*)(sVT + vb);
          accO[fv] = __builtin_amdgcn_mfma_f32_16x16x32_bf16(pa, vv, accO[fv], 0, 0, 0);
        }
      }
    }

    // ---- epilogue: attn = accO / li, written as split planes
#pragma unroll
    for (int qq = 0; qq < 4; ++qq) {
      float inv = 1.0f / li[qq];
      int n = n0 + 16 * w + 4 * hi + qq;
#pragma unroll
      for (int fv = 0; fv < 4; ++fv) {
        size_t idx = (size_t)(n * BZ + z) * DM + h * DH + 16 * fv + lo;
        float v = accO[fv][qq] * inv;
        unsigned short hb = f2bf(v);
        ohi[idx] = hb;
        olo[idx] = f2bf(v - bf2f(hb));
      }
    }
  }
}

// ---------------- launch ----------------
extern "C" void kernel_launch(void* const* d_in, const int* in_sizes, int n_in,
                              void* d_out, int out_size, void* d_ws, size_t ws_size,
                              hipStream_t stream) {
  const float* x_q   = (const float*)d_in[0];
  const float* x_kv  = (const float*)d_in[1];
  const float* to_q  = (const float*)d_in[2];
  const float* to_kv = (const float*)d_in[3];
  const float* fpe   = (const float*)d_in[4];
  const float* to_o  = (const float*)d_in[5];
  float* out = (float*)d_out;

  char* W = (char*)d_ws;
  size_t o = 0;
  auto alloc = [&](size_t bytes) { char* p = W + o; o += (bytes + 255) & ~(size_t)255; return p; };
  typedef unsigned short us;
  us* q_hi  = (us*)alloc((size_t)4096 * 1024 * 2);
  us* q_lo  = (us*)alloc((size_t)4096 * 1024 * 2);
  us* kv_hi = (us*)alloc((size_t)4096 * 2048 * 2);
  us* kv_lo = (us*)alloc((size_t)4096 * 2048 * 2);
  us* tab_hi = (us*)alloc((size_t)RTAB * 1024 * 2);
  us* tab_lo = (us*)alloc((size_t)RTAB * 1024 * 2);
  us* xq_hi = (us*)alloc((size_t)4096 * 1024 * 2);  // later: sincos hi
  us* xq_lo = (us*)alloc((size_t)4096 * 1024 * 2);  // later: sincos lo
  us* xkv_hi = (us*)alloc((size_t)4096 * 1024 * 2); // later: attn-out hi
  us* xkv_lo = (us*)alloc((size_t)4096 * 1024 * 2); // later: attn-out lo
  us* tq_hi  = (us*)alloc((size_t)1024 * 1024 * 2);
  us* tq_lo  = (us*)alloc((size_t)1024 * 1024 * 2);
  us* tkv_hi = (us*)alloc((size_t)2048 * 1024 * 2);
  us* tkv_lo = (us*)alloc((size_t)2048 * 1024 * 2);
  us* to_hi  = (us*)alloc((size_t)1024 * 1024 * 2);
  us* to_lo  = (us*)alloc((size_t)1024 * 1024 * 2);
  us* fpe_hi = (us*)alloc((size_t)1024 * 1024 * 2);
  us* fpe_lo = (us*)alloc((size_t)1024 * 1024 * 2);

  // 1. split all fp32 inputs into (hi,lo) bf16 planes
  split_kernel<<<dim3(4096 * 1024 / 4 / 256), 256, 0, stream>>>(x_q, xq_hi, xq_lo, 4096 * 1024 / 4);
  split_kernel<<<dim3(4096 * 1024 / 4 / 256), 256, 0, stream>>>(x_kv, xkv_hi, xkv_lo, 4096 * 1024 / 4);
  split_kernel<<<dim3(1024 * 1024 / 4 / 256), 256, 0, stream>>>(to_q, tq_hi, tq_lo, 1024 * 1024 / 4);
  split_kernel<<<dim3(2048 * 1024 / 4 / 256), 256, 0, stream>>>(to_kv, tkv_hi, tkv_lo, 2048 * 1024 / 4);
  split_kernel<<<dim3(1024 * 1024 / 4 / 256), 256, 0, stream>>>(to_o, to_hi, to_lo, 1024 * 1024 / 4);
  split_kernel<<<dim3(1024 * 1024 / 4 / 256), 256, 0, stream>>>(fpe, fpe_hi, fpe_lo, 1024 * 1024 / 4);

  // 2. q = x_q @ to_q^T  -> split planes
  gemm_bf16s<1><<<dim3(8, 32), 256, 0, stream>>>(xq_hi, xq_lo, tq_hi, tq_lo,
                                                 nullptr, q_hi, q_lo, 4096, 1024, 1024);
  // 3. kv = x_kv @ to_kv^T -> split planes
  gemm_bf16s<1><<<dim3(16, 32), 256, 0, stream>>>(xkv_hi, xkv_lo, tkv_hi, tkv_lo,
                                                  nullptr, kv_hi, kv_lo, 4096, 2048, 1024);
  // 4. sincos split planes (reuse xq region, now dead)
  us* sc_hi = xq_hi;
  us* sc_lo = xq_lo;
  sincos_kernel<<<dim3((MTAB * DM + 255) / 256), 256, 0, stream>>>(sc_hi, sc_lo);
  // 5. table = sincos @ fpe^T -> split planes (rows R0TAB..)
  gemm_bf16s<1><<<dim3(8, (MTAB + 127) / 128), 256, 0, stream>>>(
      sc_hi, sc_lo, fpe_hi, fpe_lo, nullptr,
      tab_hi + (size_t)R0TAB * 1024, tab_lo + (size_t)R0TAB * 1024, MTAB, 1024, 1024);
  // 6. fused attention (balanced persistent grid) -> split planes (reuse xkv region)
  us* at_hi = xkv_hi;
  us* at_lo = xkv_lo;
  attn_kernel<<<dim3(512), 256, 0, stream>>>(q_hi, q_lo, kv_hi, kv_lo,
                                             tab_hi, tab_lo, at_hi, at_lo);
  // 7. out = attn @ to_o^T -> fp32
  gemm_bf16s<0><<<dim3(8, 32), 256, 0, stream>>>(at_hi, at_lo, to_hi, to_lo,
                                                 out, nullptr, nullptr, 4096, 1024, 1024);
}

// Round 7
// 318.678 us; speedup vs baseline: 10.0462x; 1.0464x over previous
//
#include <hip/hip_runtime.h>
#include <math.h>

#define NQ 2048
#define MKV 2048
#define BZ 2
#define DM 1024
#define NH 16
#define DH 64
#define RTAB 4095  /* NQ + MKV - 1 */
#define R0TAB 1984 /* lowest table row reachable under causal mask */
#define MTAB (RTAB - R0TAB) /* 2111 */

typedef __bf16 bf16x8 __attribute__((ext_vector_type(8)));
typedef float f32x4 __attribute__((ext_vector_type(4)));

__device__ inline unsigned short f2bf(float x) {
  union { float f; unsigned u; } v; v.f = x;
  unsigned r = (v.u + 0x7FFFu + ((v.u >> 16) & 1u)) >> 16;
  return (unsigned short)r;
}
__device__ inline float bf2f(unsigned short h) {
  union { unsigned u; float f; } v; v.u = ((unsigned)h) << 16; return v.f;
}

#define SWZ(r, b) ((b) ^ (((r) & 7) << 4))
// V^T layout: conflict-free for both b16 scatter-write and b128 read
// byte addr for element (dv, m): dv*128 + ((m>>3 ^ (dv>>3)&7)<<4) + (m&7)*2
#define VSWZ(dv, m) ((dv) * 128 + (((((m) >> 3) ^ (((dv) >> 3) & 7)) << 4)) + ((m) & 7) * 2)

__device__ inline void gload_lds16(const void* g, void* l) {
  __builtin_amdgcn_global_load_lds((const __attribute__((address_space(1))) void*)g,
                                   (__attribute__((address_space(3))) void*)l, 16, 0, 0);
}

// ---------------- fp32 -> (hi,lo) bf16 split planes ----------------
__global__ __launch_bounds__(256) void split_kernel(const float* __restrict__ in,
                                                    unsigned short* __restrict__ hi,
                                                    unsigned short* __restrict__ lo,
                                                    int n4) {
  int i = blockIdx.x * 256 + threadIdx.x;
  if (i >= n4) return;
  float4 v = ((const float4*)in)[i];
  float f[4] = {v.x, v.y, v.z, v.w};
  ushort4 h4, l4;
  unsigned short* hp = (unsigned short*)&h4;
  unsigned short* lp = (unsigned short*)&l4;
#pragma unroll
  for (int e = 0; e < 4; ++e) {
    unsigned short hb = f2bf(f[e]);
    hp[e] = hb;
    lp[e] = f2bf(f[e] - bf2f(hb));
  }
  ((ushort4*)hi)[i] = h4;
  ((ushort4*)lo)[i] = l4;
}

// ---------------- sincos table, split planes (rows R0TAB..4094 as 0..2110) ----------------
__global__ __launch_bounds__(256) void sincos_kernel(unsigned short* __restrict__ hi,
                                                     unsigned short* __restrict__ lo) {
  int idx = blockIdx.x * 256 + threadIdx.x;
  if (idx >= MTAB * DM) return;
  int r = idx / DM;  // 0..2110 -> table row R0TAB + r
  int b = idx - r * DM;
  int i = (b < DM / 2) ? b : (b - DM / 2);
  double fr = exp((double)i * (-9.210340371976184 / 512.0));
  float rr = (float)(R0TAB + r - (MKV - 1));
  float ph = rr * (float)fr;
  float val = (b < DM / 2) ? sinf(ph) : cosf(ph);
  unsigned short hb = f2bf(val);
  hi[idx] = hb;
  lo[idx] = f2bf(val - bf2f(hb));
}

// ---------------- split-bf16 MFMA NT GEMM ----------------
template <int SPLIT_OUT>
__global__ __launch_bounds__(256, 2) void gemm_bf16s(
    const unsigned short* __restrict__ Ahi, const unsigned short* __restrict__ Alo,
    const unsigned short* __restrict__ Bhi, const unsigned short* __restrict__ Blo,
    float* __restrict__ Cf, unsigned short* __restrict__ Chi, unsigned short* __restrict__ Clo,
    int M, int N, int K) {
  __shared__ char lds[65536];
  char* sAh = lds;
  char* sAl = lds + 16384;
  char* sBh = lds + 32768;
  char* sBl = lds + 49152;
  const int t = threadIdx.x;
  const int w = t >> 6;
  const int lane = t & 63;
  const int lo = lane & 15;
  const int hi = lane >> 4;
  const int wm = w >> 1, wn = w & 1;
  const int row0 = blockIdx.y * 128;
  const int col0 = blockIdx.x * 128;

  f32x4 acc[4][4];
#pragma unroll
  for (int a = 0; a < 4; ++a)
#pragma unroll
    for (int b = 0; b < 4; ++b) acc[a][b] = (f32x4){0.f, 0.f, 0.f, 0.f};

  for (int k0 = 0; k0 < K; k0 += 64) {
#pragma unroll
    for (int i = 0; i < 4; ++i) {
      int L = i * 4096 + t * 16;
      int r = L >> 7;
      int c16 = (L >> 4) & 7;
      int g16 = c16 ^ (r & 7);
      int ra = row0 + r;
      if (ra >= M) ra = M - 1;
      int rb = col0 + r;
      const char* gah = (const char*)(Ahi + (size_t)ra * K + k0) + g16 * 16;
      const char* gal = (const char*)(Alo + (size_t)ra * K + k0) + g16 * 16;
      const char* gbh = (const char*)(Bhi + (size_t)rb * K + k0) + g16 * 16;
      const char* gbl = (const char*)(Blo + (size_t)rb * K + k0) + g16 * 16;
      gload_lds16(gah, sAh + L);
      gload_lds16(gal, sAl + L);
      gload_lds16(gbh, sBh + L);
      gload_lds16(gbl, sBl + L);
    }
    __syncthreads();
#pragma unroll
    for (int ks = 0; ks < 2; ++ks) {
      bf16x8 ah[4], al[4], bh[4], bl[4];
#pragma unroll
      for (int f = 0; f < 4; ++f) {
        int rA = wm * 64 + 16 * f + lo;
        int offA = rA * 128 + (((4 * ks + hi) ^ (rA & 7)) << 4);
        ah[f] = *(const bf16x8*)(sAh + offA);
        al[f] = *(const bf16x8*)(sAl + offA);
        int rB = wn * 64 + 16 * f + lo;
        int offB = rB * 128 + (((4 * ks + hi) ^ (rB & 7)) << 4);
        bh[f] = *(const bf16x8*)(sBh + offB);
        bl[f] = *(const bf16x8*)(sBl + offB);
      }
#pragma unroll
      for (int fm = 0; fm < 4; ++fm)
#pragma unroll
        for (int fn = 0; fn < 4; ++fn) {
          acc[fm][fn] = __builtin_amdgcn_mfma_f32_16x16x32_bf16(ah[fm], bh[fn], acc[fm][fn], 0, 0, 0);
          acc[fm][fn] = __builtin_amdgcn_mfma_f32_16x16x32_bf16(ah[fm], bl[fn], acc[fm][fn], 0, 0, 0);
          acc[fm][fn] = __builtin_amdgcn_mfma_f32_16x16x32_bf16(al[fm], bh[fn], acc[fm][fn], 0, 0, 0);
        }
    }
    __syncthreads();
  }
  // epilogue
#pragma unroll
  for (int fm = 0; fm < 4; ++fm)
#pragma unroll
    for (int qq = 0; qq < 4; ++qq) {
      int row = row0 + wm * 64 + 16 * fm + 4 * hi + qq;
      if (row < M) {
#pragma unroll
        for (int fn = 0; fn < 4; ++fn) {
          int col = col0 + wn * 64 + 16 * fn + lo;
          float v = acc[fm][fn][qq];
          if (SPLIT_OUT) {
            unsigned short hb = f2bf(v);
            Chi[(size_t)row * N + col] = hb;
            Clo[(size_t)row * N + col] = f2bf(v - bf2f(hb));
          } else {
            Cf[(size_t)row * N + col] = v;
          }
        }
      }
    }
}

// ---------------- MFMA fused causal attention, split-bf16 inputs ----------------
// Persistent balanced schedule: 512 blocks, block i does items {1023-i, i}.
// K/T async-staged via global_load_lds (pre-swizzled source). V reg-staged with
// conflict-free VSWZ transpose layout. PL diagonal gather fully in-register via
// width-16 shuffles (static fragment indices) -> only 2 barriers per tile.
union U8 { uint4 q; unsigned short u[8]; };

__global__ __launch_bounds__(256, 2) void attn_kernel(
    const unsigned short* __restrict__ qhi, const unsigned short* __restrict__ qlo,
    const unsigned short* __restrict__ kvhi, const unsigned short* __restrict__ kvlo,
    const unsigned short* __restrict__ tabhi, const unsigned short* __restrict__ tablo,
    unsigned short* __restrict__ ohi, unsigned short* __restrict__ olo) {
  __shared__ __align__(16) char sKhi[8192];   // K hi bf16 [64][64], swizzled
  __shared__ __align__(16) char sKlo[8192];   // K lo
  __shared__ __align__(16) char sT[32768];    // Thi [0,16K) + Tlo [16K,32K)
  __shared__ __align__(16) char sVT[8192];    // V^T bf16, VSWZ layout
  __shared__ __align__(16) char sP[8192];     // P bf16 [64 n][64 m], swizzled

  const int t = threadIdx.x;
  const int w = t >> 6;
  const int lane = t & 63;
  const int lo = lane & 15;
  const int hi = lane >> 4;

  for (int rep = 0; rep < 2; ++rep) {
    const int item = rep == 0 ? (1023 - (int)blockIdx.x) : (int)blockIdx.x;
    const int qb = item >> 5;
    const int z = (item >> 4) & 1;
    const int h = item & 15;
    const int n0 = qb * 64;

    // ---- Q fragments straight from split planes
    bf16x8 qh[2], ql[2];
    {
      size_t qoff = (size_t)((n0 + 16 * w + lo) * BZ + z) * DM + h * DH;
#pragma unroll
      for (int ks = 0; ks < 2; ++ks) {
        qh[ks] = *(const bf16x8*)(qhi + qoff + 32 * ks + 8 * hi);
        ql[ks] = *(const bf16x8*)(qlo + qoff + 32 * ks + 8 * hi);
      }
    }

    f32x4 accO[4];
#pragma unroll
    for (int f = 0; f < 4; ++f) accO[f] = (f32x4){0.f, 0.f, 0.f, 0.f};
    float mi[4], li[4];
#pragma unroll
    for (int qq = 0; qq < 4; ++qq) { mi[qq] = -1e30f; li[qq] = 0.f; }

    // V register staging (2 uint4 only)
    uint4 pVh[2];
#pragma unroll
    for (int it = 0; it < 2; ++it) {
      int f = it * 256 + t;
      int j = f >> 3;
      int d8 = (f & 7) << 3;
      size_t gb = (size_t)((0 + j) * BZ + z) * (NH * 2 * DH) + h * (2 * DH);
      pVh[it] = *(const uint4*)(kvhi + gb + DH + d8);
    }

    for (int mt = 0; mt <= qb; ++mt) {
      const int m0 = mt * 64;
      const int Wb = n0 - m0 + R0TAB;
      __syncthreads();  // prior tile's LDS reads complete before restaging

      // ---- async stage K hi/lo (pre-swizzled source -> linear LDS dest)
#pragma unroll
      for (int it = 0; it < 2; ++it) {
        int f = it * 256 + t;
        int j = f >> 3;        // 0..63
        int c = f & 7;         // 16B chunk
        int gsw = (c ^ (j & 7)) << 3;  // element offset of swizzled chunk
        size_t gb = (size_t)((m0 + j) * BZ + z) * (NH * 2 * DH) + h * (2 * DH);
        gload_lds16(kvhi + gb + gsw, sKhi + f * 16);
        gload_lds16(kvlo + gb + gsw, sKlo + f * 16);
      }
      // ---- async stage T window hi/lo (128 rows; row 127 clamped, never read)
#pragma unroll
      for (int it = 0; it < 4; ++it) {
        int f = it * 256 + t;
        int rr = f >> 3;       // 0..127
        int rc = rr < 127 ? rr : 126;
        int c = f & 7;
        int gsw = (c ^ (rr & 7)) << 3;
        size_t gb = (size_t)(Wb + rc) * DM + h * DH;
        gload_lds16(tabhi + gb + gsw, sT + f * 16);
        gload_lds16(tablo + gb + gsw, sT + 16384 + f * 16);
      }

      // ---- write this tile's V^T from regs (conflict-free VSWZ layout)
#pragma unroll
      for (int it = 0; it < 2; ++it) {
        int f = it * 256 + t;
        int j = f >> 3;
        int d8 = (f & 7) << 3;
        U8 vh;
        vh.q = pVh[it];
#pragma unroll
        for (int e = 0; e < 8; ++e) {
          int dv = d8 + e;
          *(unsigned short*)(sVT + VSWZ(dv, j)) = vh.u[e];
        }
      }
      // ---- issue next tile's V loads (land during this tile's compute)
      if (mt < qb) {
        const int m0n = (mt + 1) * 64;
#pragma unroll
        for (int it = 0; it < 2; ++it) {
          int f = it * 256 + t;
          int j = f >> 3;
          int d8 = (f & 7) << 3;
          size_t gb = (size_t)((m0n + j) * BZ + z) * (NH * 2 * DH) + h * (2 * DH);
          pVh[it] = *(const uint4*)(kvhi + gb + DH + d8);
        }
      }
      __syncthreads();  // drains gload_lds (vmcnt) + V^T ds writes

      // ---- S = QK^T and PL = QT^T, split-bf16 MFMA
      f32x4 accS[4], accPL[5];
#pragma unroll
      for (int f = 0; f < 4; ++f) accS[f] = (f32x4){0.f, 0.f, 0.f, 0.f};
#pragma unroll
      for (int f = 0; f < 5; ++f) accPL[f] = (f32x4){0.f, 0.f, 0.f, 0.f};
#pragma unroll
      for (int ks = 0; ks < 2; ++ks) {
#pragma unroll
        for (int fm = 0; fm < 4; ++fm) {
          int rb = SWZ(lo, (16 * fm + lo) * 128 + (32 * ks + 8 * hi) * 2);
          bf16x8 kh = *(const bf16x8*)(sKhi + rb);
          bf16x8 kl = *(const bf16x8*)(sKlo + rb);
          accS[fm] = __builtin_amdgcn_mfma_f32_16x16x32_bf16(qh[ks], kh, accS[fm], 0, 0, 0);
          accS[fm] = __builtin_amdgcn_mfma_f32_16x16x32_bf16(qh[ks], kl, accS[fm], 0, 0, 0);
          accS[fm] = __builtin_amdgcn_mfma_f32_16x16x32_bf16(ql[ks], kh, accS[fm], 0, 0, 0);
        }
#pragma unroll
        for (int fr = 0; fr < 5; ++fr) {
          int r = 16 * (w + fr) + lo;
          int rb = SWZ(lo, r * 128 + (32 * ks + 8 * hi) * 2);
          bf16x8 th = *(const bf16x8*)(sT + rb);
          bf16x8 tl = *(const bf16x8*)(sT + 16384 + rb);
          accPL[fr] = __builtin_amdgcn_mfma_f32_16x16x32_bf16(qh[ks], th, accPL[fr], 0, 0, 0);
          accPL[fr] = __builtin_amdgcn_mfma_f32_16x16x32_bf16(qh[ks], tl, accPL[fr], 0, 0, 0);
          accPL[fr] = __builtin_amdgcn_mfma_f32_16x16x32_bf16(ql[ks], th, accPL[fr], 0, 0, 0);
        }
      }

      // ---- PL diagonal gather, fully in-register via width-16 shuffles.
      // rn = 4hi+qq+63-16fm-lo in [48-16fm, 78-16fm] -> fragment in {3-fm, 4-fm} (static).
#pragma unroll
      for (int fm = 0; fm < 4; ++fm)
#pragma unroll
        for (int qq = 0; qq < 4; ++qq) {
          int rn = 4 * hi + qq + 63 - 16 * fm - lo;
          float va = __shfl(accPL[3 - fm][qq], rn & 15, 16);
          float vb = __shfl(accPL[4 - fm][qq], rn & 15, 16);
          accS[fm][qq] += (rn >> 4) == (3 - fm) ? va : vb;
        }

      if (mt == qb) {  // diagonal tile: mask m > n
#pragma unroll
        for (int fm = 0; fm < 4; ++fm)
#pragma unroll
          for (int qq = 0; qq < 4; ++qq)
            if (16 * fm + lo > 16 * w + 4 * hi + qq) accS[fm][qq] = -1e30f;
      }

      // ---- online softmax in registers
#pragma unroll
      for (int qq = 0; qq < 4; ++qq) {
        float pm = fmaxf(fmaxf(accS[0][qq], accS[1][qq]), fmaxf(accS[2][qq], accS[3][qq]));
        pm = fmaxf(pm, __shfl_xor(pm, 1));
        pm = fmaxf(pm, __shfl_xor(pm, 2));
        pm = fmaxf(pm, __shfl_xor(pm, 4));
        pm = fmaxf(pm, __shfl_xor(pm, 8));
        float mn = fmaxf(mi[qq], pm);
        float a = __expf(mi[qq] - mn);
        mi[qq] = mn;
        float rs = 0.f;
#pragma unroll
        for (int fm = 0; fm < 4; ++fm) {
          float p = __expf(accS[fm][qq] - mn);
          accS[fm][qq] = p;
          rs += p;
        }
        rs += __shfl_xor(rs, 1);
        rs += __shfl_xor(rs, 2);
        rs += __shfl_xor(rs, 4);
        rs += __shfl_xor(rs, 8);
        li[qq] = li[qq] * a + rs;
#pragma unroll
        for (int f = 0; f < 4; ++f) accO[f][qq] *= a;
      }

      // ---- P -> LDS bf16 (wave-local rows)
#pragma unroll
      for (int fm = 0; fm < 4; ++fm)
#pragma unroll
        for (int qq = 0; qq < 4; ++qq) {
          int row = 16 * w + 4 * hi + qq;
          *(unsigned short*)(sP + SWZ(4 * hi + qq, row * 128 + (16 * fm + lo) * 2)) =
              f2bf(accS[fm][qq]);
        }

      // ---- PV: accO += P @ V
#pragma unroll
      for (int ks = 0; ks < 2; ++ks) {
        int ab = SWZ(lo, (16 * w + lo) * 128 + (32 * ks + 8 * hi) * 2);
        bf16x8 pa = *(const bf16x8*)(sP + ab);
#pragma unroll
        for (int fv = 0; fv < 4; ++fv) {
          int dv = 16 * fv + lo;
          int vb = dv * 128 + (((4 * ks + hi) ^ ((dv >> 3) & 7)) << 4);
          bf16x8 vv = *(const bf16x8*)(sVT + vb);
          accO[fv] = __builtin_amdgcn_mfma_f32_16x16x32_bf16(pa, vv, accO[fv], 0, 0, 0);
        }
      }
    }

    // ---- epilogue: attn = accO / li, written as split planes
#pragma unroll
    for (int qq = 0; qq < 4; ++qq) {
      float inv = 1.0f / li[qq];
      int n = n0 + 16 * w + 4 * hi + qq;
#pragma unroll
      for (int fv = 0; fv < 4; ++fv) {
        size_t idx = (size_t)(n * BZ + z) * DM + h * DH + 16 * fv + lo;
        float v = accO[fv][qq] * inv;
        unsigned short hb = f2bf(v);
        ohi[idx] = hb;
        olo[idx] = f2bf(v - bf2f(hb));
      }
    }
  }
}

// ---------------- launch ----------------
extern "C" void kernel_launch(void* const* d_in, const int* in_sizes, int n_in,
                              void* d_out, int out_size, void* d_ws, size_t ws_size,
                              hipStream_t stream) {
  const float* x_q   = (const float*)d_in[0];
  const float* x_kv  = (const float*)d_in[1];
  const float* to_q  = (const float*)d_in[2];
  const float* to_kv = (const float*)d_in[3];
  const float* fpe   = (const float*)d_in[4];
  const float* to_o  = (const float*)d_in[5];
  float* out = (float*)d_out;

  char* W = (char*)d_ws;
  size_t o = 0;
  auto alloc = [&](size_t bytes) { char* p = W + o; o += (bytes + 255) & ~(size_t)255; return p; };
  typedef unsigned short us;
  us* q_hi  = (us*)alloc((size_t)4096 * 1024 * 2);
  us* q_lo  = (us*)alloc((size_t)4096 * 1024 * 2);
  us* kv_hi = (us*)alloc((size_t)4096 * 2048 * 2);
  us* kv_lo = (us*)alloc((size_t)4096 * 2048 * 2);
  us* tab_hi = (us*)alloc((size_t)RTAB * 1024 * 2);
  us* tab_lo = (us*)alloc((size_t)RTAB * 1024 * 2);
  us* xq_hi = (us*)alloc((size_t)4096 * 1024 * 2);  // later: sincos hi
  us* xq_lo = (us*)alloc((size_t)4096 * 1024 * 2);  // later: sincos lo
  us* xkv_hi = (us*)alloc((size_t)4096 * 1024 * 2); // later: attn-out hi
  us* xkv_lo = (us*)alloc((size_t)4096 * 1024 * 2); // later: attn-out lo
  us* tq_hi  = (us*)alloc((size_t)1024 * 1024 * 2);
  us* tq_lo  = (us*)alloc((size_t)1024 * 1024 * 2);
  us* tkv_hi = (us*)alloc((size_t)2048 * 1024 * 2);
  us* tkv_lo = (us*)alloc((size_t)2048 * 1024 * 2);
  us* to_hi  = (us*)alloc((size_t)1024 * 1024 * 2);
  us* to_lo  = (us*)alloc((size_t)1024 * 1024 * 2);
  us* fpe_hi = (us*)alloc((size_t)1024 * 1024 * 2);
  us* fpe_lo = (us*)alloc((size_t)1024 * 1024 * 2);

  // 1. split all fp32 inputs into (hi,lo) bf16 planes
  split_kernel<<<dim3(4096 * 1024 / 4 / 256), 256, 0, stream>>>(x_q, xq_hi, xq_lo, 4096 * 1024 / 4);
  split_kernel<<<dim3(4096 * 1024 / 4 / 256), 256, 0, stream>>>(x_kv, xkv_hi, xkv_lo, 4096 * 1024 / 4);
  split_kernel<<<dim3(1024 * 1024 / 4 / 256), 256, 0, stream>>>(to_q, tq_hi, tq_lo, 1024 * 1024 / 4);
  split_kernel<<<dim3(2048 * 1024 / 4 / 256), 256, 0, stream>>>(to_kv, tkv_hi, tkv_lo, 2048 * 1024 / 4);
  split_kernel<<<dim3(1024 * 1024 / 4 / 256), 256, 0, stream>>>(to_o, to_hi, to_lo, 1024 * 1024 / 4);
  split_kernel<<<dim3(1024 * 1024 / 4 / 256), 256, 0, stream>>>(fpe, fpe_hi, fpe_lo, 1024 * 1024 / 4);

  // 2. q = x_q @ to_q^T  -> split planes
  gemm_bf16s<1><<<dim3(8, 32), 256, 0, stream>>>(xq_hi, xq_lo, tq_hi, tq_lo,
                                                 nullptr, q_hi, q_lo, 4096, 1024, 1024);
  // 3. kv = x_kv @ to_kv^T -> split planes
  gemm_bf16s<1><<<dim3(16, 32), 256, 0, stream>>>(xkv_hi, xkv_lo, tkv_hi, tkv_lo,
                                                  nullptr, kv_hi, kv_lo, 4096, 2048, 1024);
  // 4. sincos split planes (reuse xq region, now dead)
  us* sc_hi = xq_hi;
  us* sc_lo = xq_lo;
  sincos_kernel<<<dim3((MTAB * DM + 255) / 256), 256, 0, stream>>>(sc_hi, sc_lo);
  // 5. table = sincos @ fpe^T -> split planes (rows R0TAB..)
  gemm_bf16s<1><<<dim3(8, (MTAB + 127) / 128), 256, 0, stream>>>(
      sc_hi, sc_lo, fpe_hi, fpe_lo, nullptr,
      tab_hi + (size_t)R0TAB * 1024, tab_lo + (size_t)R0TAB * 1024, MTAB, 1024, 1024);
  // 6. fused attention (balanced persistent grid) -> split planes (reuse xkv region)
  us* at_hi = xkv_hi;
  us* at_lo = xkv_lo;
  attn_kernel<<<dim3(512), 256, 0, stream>>>(q_hi, q_lo, kv_hi, kv_lo,
                                             tab_hi, tab_lo, at_hi, at_lo);
  // 7. out = attn @ to_o^T -> fp32
  gemm_bf16s<0><<<dim3(8, 32), 256, 0, stream>>>(at_hi, at_lo, to_hi, to_lo,
                                                 out, nullptr, nullptr, 4096, 1024, 1024);
}